// Round 4
// baseline (319.305 us; speedup 1.0000x reference)
//
#include <hip/hip_runtime.h>
#include <hip/hip_cooperative_groups.h>

namespace cg = cooperative_groups;

#define N_NODES 50000
#define N_EDGES 800000
#define D 64
#define NBUCKETS 196          // dst>>8, 0..195
#define BCAP 8192             // fixed bucket capacity (Poisson(4082), 5sigma<4400)
#define SBLOCKS 256           // scatter blocks
#define CHUNK (N_EDGES / SBLOCKS)   // 3125
#define MB ((N_NODES + 63) / 64)    // 782 gemm tiles

// bf16 helpers (RNE), bit-level.
__device__ __forceinline__ unsigned short f2bf(float f) {
    unsigned u = __float_as_uint(f);
    return (unsigned short)((u + 0x7fffu + ((u >> 16) & 1u)) >> 16);
}
__device__ __forceinline__ float bflo(unsigned u) {
    return __uint_as_float(u << 16);
}
__device__ __forceinline__ float bfhi(unsigned u) {
    return __uint_as_float(u & 0xffff0000u);
}

// ---------- scatter body (verified R1 form; LDS passed in) ------------------
__device__ __forceinline__ void scatter_body(
    const int* __restrict__ src, const int* __restrict__ dst,
    int* __restrict__ cursorPad, int* __restrict__ staged,
    char* smem, int bid, int t) {
    int* hist = (int*)smem;                       // 256 ints
    int* curs = (int*)(smem + 1024);              // 256 ints
    int* pk   = (int*)(smem + 2048);              // CHUNK ints
    unsigned char* bk = (unsigned char*)(smem + 2048 + CHUNK * 4);
    hist[t] = 0;
    __syncthreads();
    int lo = bid * CHUNK;
    for (int i = t; i < CHUNK; i += 256) {
        int d = dst[lo + i];
        int s = src[lo + i];
        pk[i] = (s << 8) | (d & 255);
        bk[i] = (unsigned char)(d >> 8);
        atomicAdd(&hist[d >> 8], 1);
    }
    __syncthreads();
    if (hist[t] > 0)
        curs[t] = t * BCAP + atomicAdd(&cursorPad[t * 16], hist[t]);
    __syncthreads();
    for (int i = t; i < CHUNK; i += 256) {
        int b = bk[i];
        int pos = atomicAdd(&curs[b], 1);
        staged[pos] = pk[i];
    }
}

// ---------- csr body (verified R3 form: LDS image, coalesced flush) ---------
__device__ __forceinline__ void csr_body(
    const int* __restrict__ cursorPad, const int* __restrict__ staged,
    int* __restrict__ csr, int* __restrict__ startA, int* __restrict__ endA,
    char* smem, int k, int t) {
    int* deg  = (int*)smem;                 // 256 ints
    int* sc   = (int*)(smem + 1024);        // 256 ints
    int* curs = (int*)(smem + 2048);        // 256 ints
    int* lcsr = (int*)(smem + 3072);        // BCAP ints (32 KB)
    int base = k * BCAP;
    int cnt  = cursorPad[k * 16];
    deg[t] = 0;
    __syncthreads();
    for (int i = t; i < cnt; i += 256)
        atomicAdd(&deg[staged[base + i] & 255], 1);
    __syncthreads();
    int v = deg[t];
    sc[t] = v;
    __syncthreads();
#pragma unroll
    for (int d = 1; d < 256; d <<= 1) {
        int u = (t >= d) ? sc[t - d] : 0;
        __syncthreads();
        sc[t] += u;
        __syncthreads();
    }
    int start = sc[t] - v;
    int node = k * 256 + t;
    if (node < N_NODES) {
        startA[node] = base + start;
        endA[node]   = base + start + v;
    }
    curs[t] = start;
    __syncthreads();
    for (int i = t; i < cnt; i += 256) {
        int e = staged[base + i];
        int pos = atomicAdd(&curs[e & 255], 1);
        lcsr[pos] = e >> 8;                    // LDS scatter (fast)
    }
    __syncthreads();
    for (int i = t; i < cnt; i += 256)         // coalesced flush
        csr[base + i] = lcsr[i];
}

// ---------- dual-output GEMM body: R = X@Wr (fp32), Nn = X@Wn (bf16) --------
template<int XBF>
__device__ __forceinline__ void gemm_body(
    const float* __restrict__ Xf, const unsigned short* __restrict__ Xb,
    const float* __restrict__ Wr, const float* __restrict__ Wn,
    float* __restrict__ outR, unsigned short* __restrict__ outN,
    int node0, int tid, char* smem) {
    float (*sXT)[D] = (float(*)[D])smem;             // 16 KB
    float (*sWr)[D] = (float(*)[D])(smem + 16384);   // 16 KB
    float (*sWn)[D] = (float(*)[D])(smem + 32768);   // 16 KB

#pragma unroll
    for (int i = 0; i < 4; i++) {
        int idx = tid + 256 * i;
        ((float4*)sWr)[idx] = ((const float4*)Wr)[idx];
        ((float4*)sWn)[idx] = ((const float4*)Wn)[idx];
    }
    int nd = tid & 63;
    int gn = min(node0 + nd, N_NODES - 1);
    if (XBF) {
#pragma unroll
        for (int pass = 0; pass < 2; pass++) {
            int kg = (tid >> 6) + pass * 4;       // 0..7
            int k0 = kg * 8;
            uint4 ux = *(const uint4*)(Xb + (size_t)gn * D + k0);
            sXT[k0 + 0][nd] = bflo(ux.x); sXT[k0 + 1][nd] = bfhi(ux.x);
            sXT[k0 + 2][nd] = bflo(ux.y); sXT[k0 + 3][nd] = bfhi(ux.y);
            sXT[k0 + 4][nd] = bflo(ux.z); sXT[k0 + 5][nd] = bfhi(ux.z);
            sXT[k0 + 6][nd] = bflo(ux.w); sXT[k0 + 7][nd] = bfhi(ux.w);
        }
    } else {
        const float4* X4 = (const float4*)Xf;
#pragma unroll
        for (int pass = 0; pass < 4; pass++) {
            int kq = (tid >> 6) + pass * 4;
            float4 v = X4[gn * 16 + kq];
            sXT[kq * 4 + 0][nd] = v.x; sXT[kq * 4 + 1][nd] = v.y;
            sXT[kq * 4 + 2][nd] = v.z; sXT[kq * 4 + 3][nd] = v.w;
        }
    }
    __syncthreads();

    int nq = tid >> 4;
    int cq = tid & 15;
    float accR[4][4];
    float accN[4][4];
#pragma unroll
    for (int i = 0; i < 4; i++)
#pragma unroll
        for (int jj = 0; jj < 4; jj++) { accR[i][jj] = 0.f; accN[i][jj] = 0.f; }

#pragma unroll 16
    for (int k = 0; k < D; k++) {
        float4 xv = *(const float4*)&sXT[k][nq * 4];
        float4 wr = *(const float4*)&sWr[k][cq * 4];
        float4 wn = *(const float4*)&sWn[k][cq * 4];
        float xs[4] = {xv.x, xv.y, xv.z, xv.w};
        float rs[4] = {wr.x, wr.y, wr.z, wr.w};
        float ns[4] = {wn.x, wn.y, wn.z, wn.w};
#pragma unroll
        for (int i = 0; i < 4; i++)
#pragma unroll
            for (int jj = 0; jj < 4; jj++) {
                accR[i][jj] = fmaf(xs[i], rs[jj], accR[i][jj]);
                accN[i][jj] = fmaf(xs[i], ns[jj], accN[i][jj]);
            }
    }

    float4* outR4 = (float4*)outR;
#pragma unroll
    for (int i = 0; i < 4; i++) {
        int node = node0 + nq * 4 + i;
        if (node < N_NODES) {
            float4 r;
            r.x = accR[i][0]; r.y = accR[i][1];
            r.z = accR[i][2]; r.w = accR[i][3];
            outR4[node * 16 + cq] = r;
            ushort4 rb;
            rb.x = f2bf(accN[i][0]); rb.y = f2bf(accN[i][1]);
            rb.z = f2bf(accN[i][2]); rb.w = f2bf(accN[i][3]);
            *(ushort4*)(outN + (size_t)node * D + cq * 4) = rb;
        }
    }
}

// ---------- cooperative front kernel: memset + [scatter || gemm1] + csr -----
// Requires cooperative launch (co-residency) — grid.sync for phase ordering.
__global__ void __launch_bounds__(256) fused_front(
    const int* __restrict__ src, const int* __restrict__ dst,
    int* __restrict__ cursorPad, int* __restrict__ staged,
    const float* __restrict__ X,
    const float* __restrict__ Wr, const float* __restrict__ Wn,
    float* __restrict__ xr, unsigned short* __restrict__ xn,
    int* __restrict__ csr, int* __restrict__ startA, int* __restrict__ endA) {
    cg::grid_group g = cg::this_grid();
    __shared__ char smem[49152];
    int t = threadIdx.x;
    int bid = blockIdx.x;

    if (bid == 0)
        for (int i = t; i < 4096; i += 256) cursorPad[i] = 0;
    g.sync();                                   // cursors zeroed

    if (bid < SBLOCKS) {
        scatter_body(src, dst, cursorPad, staged, smem, bid, t);
        __threadfence();
    } else {
        int nblk = (int)gridDim.x - SBLOCKS;
        for (int tile = bid - SBLOCKS; tile < MB; tile += nblk) {
            __syncthreads();                    // protect LDS reuse across tiles
            gemm_body<0>(X, (const unsigned short*)0, Wr, Wn, xr, xn,
                         tile * 64, t, smem);
        }
    }
    g.sync();                                   // staged[] + cursors complete

    if (bid < NBUCKETS)
        csr_body(cursorPad, staged, csr, startA, endA, smem, bid, t);
}

// ---------- fallback path (verified R3 kernels) -----------------------------
__global__ void __launch_bounds__(256) scatter_gemm1(
    const int* __restrict__ src, const int* __restrict__ dst,
    int* __restrict__ cursorPad, int* __restrict__ staged,
    const float* __restrict__ X,
    const float* __restrict__ Wr, const float* __restrict__ Wn,
    float* __restrict__ xr, unsigned short* __restrict__ xn) {
    __shared__ char smem[49152];
    if (blockIdx.x < SBLOCKS) {
        scatter_body(src, dst, cursorPad, staged, smem, blockIdx.x, threadIdx.x);
    } else {
        gemm_body<0>(X, (const unsigned short*)0, Wr, Wn, xr, xn,
                     (blockIdx.x - SBLOCKS) * 64, threadIdx.x, smem);
    }
}

__global__ void __launch_bounds__(256) csr_build_kernel(
    const int* __restrict__ cursorPad, const int* __restrict__ staged,
    int* __restrict__ csr, int* __restrict__ startA, int* __restrict__ endA) {
    __shared__ char smem[49152];
    csr_body(cursorPad, staged, csr, startA, endA, smem,
             blockIdx.x, threadIdx.x);
}

// ---------- standalone layer-2 GEMM (bf16 input) ----------------------------
__global__ void __launch_bounds__(256) gemm2(
    const unsigned short* __restrict__ Xb,
    const float* __restrict__ Wr, const float* __restrict__ Wn,
    float* __restrict__ hr, unsigned short* __restrict__ hn) {
    __shared__ char smem[49152];
    gemm_body<1>((const float*)0, Xb, Wr, Wn, hr, hn,
                 blockIdx.x * 64, threadIdx.x, smem);
}

// ---------- Gather (uint4 / 8-lane-row-group) + fused epilogue --------------
template<int RELU, int OUTBF>
__global__ void __launch_bounds__(256) gather_fused(
    const unsigned short* __restrict__ Gsrc, const float* __restrict__ Root,
    const float* __restrict__ bias,
    const int* __restrict__ startA, const int* __restrict__ endA,
    const int* __restrict__ csr,
    float* __restrict__ outF, unsigned short* __restrict__ outB) {
    int tid = threadIdx.x;
    int wave = tid >> 6, lane = tid & 63;
    int node = blockIdx.x * 4 + wave;
    int sub = lane >> 3, fq = lane & 7;
    int j0 = startA[node], je = endA[node];
    float a0=0.f,a1=0.f,a2=0.f,a3=0.f,a4=0.f,a5=0.f,a6=0.f,a7=0.f;
    for (int jb = j0; jb < je; jb += 64) {          // je wave-uniform
        int idx = jb + lane;
        int p = csr[idx < je ? idx : (je - 1)];     // coalesced index batch
        int m = min(64, je - jb);                   // wave-uniform
        int b = 0;
        for (; b + 16 <= m; b += 16) {
            int i0 = __shfl(p, b + sub, 64);
            int i1 = __shfl(p, b + 8 + sub, 64);
            uint4 u0 = *(const uint4*)(Gsrc + i0 * D + fq * 8);
            uint4 u1 = *(const uint4*)(Gsrc + i1 * D + fq * 8);
            a0 += bflo(u0.x) + bflo(u1.x);  a1 += bfhi(u0.x) + bfhi(u1.x);
            a2 += bflo(u0.y) + bflo(u1.y);  a3 += bfhi(u0.y) + bfhi(u1.y);
            a4 += bflo(u0.z) + bflo(u1.z);  a5 += bfhi(u0.z) + bfhi(u1.z);
            a6 += bflo(u0.w) + bflo(u1.w);  a7 += bfhi(u0.w) + bfhi(u1.w);
        }
        for (; b < m; b += 8) {                     // uniform condition
            int sidx = b + sub;
            int scl = sidx < m ? sidx : (m - 1);    // active source lane
            int i0 = __shfl(p, scl, 64);            // executed by ALL lanes
            if (sidx < m) {                         // divergence only here
                uint4 u = *(const uint4*)(Gsrc + i0 * D + fq * 8);
                a0 += bflo(u.x); a1 += bfhi(u.x);
                a2 += bflo(u.y); a3 += bfhi(u.y);
                a4 += bflo(u.z); a5 += bfhi(u.z);
                a6 += bflo(u.w); a7 += bfhi(u.w);
            }
        }
    }
#pragma unroll
    for (int mk = 8; mk <= 32; mk <<= 1) {
        a0 += __shfl_xor(a0, mk, 64); a1 += __shfl_xor(a1, mk, 64);
        a2 += __shfl_xor(a2, mk, 64); a3 += __shfl_xor(a3, mk, 64);
        a4 += __shfl_xor(a4, mk, 64); a5 += __shfl_xor(a5, mk, 64);
        a6 += __shfl_xor(a6, mk, 64); a7 += __shfl_xor(a7, mk, 64);
    }
    if (sub == 0) {
        const float* rp = Root + (size_t)node * D + fq * 8;
        float4 x0 = *(const float4*)rp;
        float4 x1 = *(const float4*)(rp + 4);
        float4 b0 = ((const float4*)bias)[fq * 2];
        float4 b1 = ((const float4*)bias)[fq * 2 + 1];
        float r0 = a0 + x0.x + b0.x, r1 = a1 + x0.y + b0.y;
        float r2 = a2 + x0.z + b0.z, r3 = a3 + x0.w + b0.w;
        float r4 = a4 + x1.x + b1.x, r5 = a5 + x1.y + b1.y;
        float r6 = a6 + x1.z + b1.z, r7 = a7 + x1.w + b1.w;
        if (RELU) {
            r0 = fmaxf(r0, 0.f); r1 = fmaxf(r1, 0.f);
            r2 = fmaxf(r2, 0.f); r3 = fmaxf(r3, 0.f);
            r4 = fmaxf(r4, 0.f); r5 = fmaxf(r5, 0.f);
            r6 = fmaxf(r6, 0.f); r7 = fmaxf(r7, 0.f);
        }
        if (OUTBF) {
            uint4 u;
            u.x = (unsigned)f2bf(r0) | ((unsigned)f2bf(r1) << 16);
            u.y = (unsigned)f2bf(r2) | ((unsigned)f2bf(r3) << 16);
            u.z = (unsigned)f2bf(r4) | ((unsigned)f2bf(r5) << 16);
            u.w = (unsigned)f2bf(r6) | ((unsigned)f2bf(r7) << 16);
            *(uint4*)(outB + (size_t)node * D + fq * 8) = u;
        } else {
            float4 w0; w0.x = r0; w0.y = r1; w0.z = r2; w0.w = r3;
            float4 w1; w1.x = r4; w1.y = r5; w1.z = r6; w1.w = r7;
            *(float4*)(outF + (size_t)node * D + fq * 8) = w0;
            *(float4*)(outF + (size_t)node * D + fq * 8 + 4) = w1;
        }
    }
}

// ---------- launch ----------------------------------------------------------
extern "C" void kernel_launch(void* const* d_in, const int* in_sizes, int n_in,
                              void* d_out, int out_size, void* d_ws, size_t ws_size,
                              hipStream_t stream) {
    const float* x   = (const float*)d_in[0];
    const int*   edg = (const int*)d_in[1];
    const float* W1r = (const float*)d_in[2];
    const float* W1n = (const float*)d_in[3];
    const float* b1  = (const float*)d_in[4];
    const float* W2r = (const float*)d_in[5];
    const float* W2n = (const float*)d_in[6];
    const float* b2  = (const float*)d_in[7];
    float* out = (float*)d_out;

    const int* src = edg;
    const int* dst = edg + N_EDGES;

    // ws (256 MiB) — non-overlapping padded layout.
    int* W              = (int*)d_ws;
    int* cursorPad      = W;                         // 196*16 ints (4096 zeroed)
    int* staged         = W + 4096;                  // NBUCKETS*BCAP
    int* csr            = staged + NBUCKETS * BCAP;  // NBUCKETS*BCAP
    int* startA         = csr + NBUCKETS * BCAP;
    int* endA           = startA + N_NODES;
    float* xr           = (float*)(endA + N_NODES);  // fp32 [N][64] root L1
    unsigned short* xn  = (unsigned short*)(xr + (size_t)N_NODES * D); // bf16 x@W1n
    unsigned short* hbf = xn + (size_t)N_NODES * D;  // bf16 h
    float* hr           = (float*)(hbf + (size_t)N_NODES * D);        // fp32 h@W2r
    unsigned short* hn  = (unsigned short*)(hr + (size_t)N_NODES * D); // bf16 h@W2n

    // ---- front: cooperative fused kernel, else verified 3-dispatch fallback.
    bool coop_ok = false;
    int maxb = 0;
    if (hipOccupancyMaxActiveBlocksPerMultiprocessor(
            &maxb, (const void*)fused_front, 256, 0) == hipSuccess && maxb > 0) {
        int grid = maxb * 256;                       // 256 CUs on MI355X
        if (grid > 768) grid = 768;                  // 3 blocks/CU at 48KB LDS
        if (grid >= SBLOCKS + 64) {                  // need gemm role blocks
            void* args[] = {(void*)&src, (void*)&dst, (void*)&cursorPad,
                            (void*)&staged, (void*)&x, (void*)&W1r, (void*)&W1n,
                            (void*)&xr, (void*)&xn, (void*)&csr, (void*)&startA,
                            (void*)&endA};
            hipError_t e = hipLaunchCooperativeKernel(
                (const void*)fused_front, dim3(grid), dim3(256), args, 0, stream);
            coop_ok = (e == hipSuccess);
        }
    }
    if (!coop_ok) {
        hipMemsetAsync(cursorPad, 0, 196 * 16 * sizeof(int), stream);
        scatter_gemm1<<<SBLOCKS + MB, 256, 0, stream>>>(
            src, dst, cursorPad, staged, x, W1r, W1n, xr, xn);
        csr_build_kernel<<<NBUCKETS, 256, 0, stream>>>(cursorPad, staged, csr,
                                                       startA, endA);
    }

    const int GB = N_NODES / 4;          // 12500

    // h = relu(xr + segsum(xn[src]) + b1), written bf16.
    gather_fused<1, 1><<<GB, 256, 0, stream>>>(
        xn, xr, b1, startA, endA, csr, (float*)0, hbf);

    // layer-2 dual GEMM: hr = h@W2r fp32, hn = h@W2n bf16.
    gemm2<<<MB, 256, 0, stream>>>(hbf, W2r, W2n, hr, hn);

    // out = hr + segsum(hn[src]) + b2, written fp32.
    gather_fused<0, 0><<<GB, 256, 0, stream>>>(
        hn, hr, b2, startA, endA, csr, out, (unsigned short*)0);
}

// Round 5
// 184.034 us; speedup vs baseline: 1.7350x; 1.7350x over previous
//
#include <hip/hip_runtime.h>

#define N_NODES 50000
#define N_EDGES 800000
#define D 64
#define NBUCKETS 196          // dst>>8, 0..195
#define SBLOCKS 256           // scatter blocks
#define CHUNK (N_EDGES / SBLOCKS)   // 3125 edges per scatter block
#define SLOT 44               // per-(block,bucket) slot (Poisson(15.9), 7sigma)
#define SREG (SBLOCKS * SLOT) // 11264 ints per bucket in staged
#define CCAP 8192             // csr per-bucket capacity (Poisson(4082), 5sigma<4400)
#define MB ((N_NODES + 63) / 64)    // 782 gemm tiles

// bf16 helpers (RNE), bit-level.
__device__ __forceinline__ unsigned short f2bf(float f) {
    unsigned u = __float_as_uint(f);
    return (unsigned short)((u + 0x7fffu + ((u >> 16) & 1u)) >> 16);
}
__device__ __forceinline__ float bflo(unsigned u) {
    return __uint_as_float(u << 16);
}
__device__ __forceinline__ float bfhi(unsigned u) {
    return __uint_as_float(u & 0xffff0000u);
}

// ---------- single-pass atomic-free slotted scatter -------------------------
// Block b: edge -> staged[k*SREG + b*SLOT + lpos], lpos from LDS counter.
// Writes cnts[k*256+b] for ALL k (fully overwritten -> no memset needed).
__device__ __forceinline__ void scatter_body(
    const int* __restrict__ src, const int* __restrict__ dst,
    int* __restrict__ cnts, int* __restrict__ staged,
    char* smem, int bid, int t) {
    int* hist = (int*)smem;                       // 256 ints
    hist[t] = 0;
    __syncthreads();
    int lo = bid * CHUNK;
    for (int i = t; i < CHUNK; i += 256) {
        int d = dst[lo + i];
        int s = src[lo + i];
        int k = d >> 8;
        int lpos = atomicAdd(&hist[k], 1);
        if (lpos < SLOT)                          // 7-sigma guard (never taken)
            staged[k * SREG + bid * SLOT + lpos] = (s << 8) | (d & 255);
    }
    __syncthreads();
    if (t < NBUCKETS)
        cnts[t * 256 + bid] = min(hist[t], SLOT);
}

// ---------- per-bucket CSR build from slotted staging -----------------------
// Reads its cnts row (coalesced), deg-counts over the slot space, node-prefix
// scan (verified form), places edges into an LDS image, coalesced flush.
// csr/startA/endA layout identical to the verified R3 version.
__device__ __forceinline__ void csr_body(
    const int* __restrict__ cnts, const int* __restrict__ staged,
    int* __restrict__ csr, int* __restrict__ startA, int* __restrict__ endA,
    char* smem, int k, int t) {
    int* deg  = (int*)smem;                 // 256 ints
    int* sc   = (int*)(smem + 1024);        // 256 ints
    int* curs = (int*)(smem + 2048);        // 256 ints
    int* crow = (int*)(smem + 3072);        // 256 ints (per-block counts)
    int* lcsr = (int*)(smem + 4096);        // CCAP ints (32 KB image)
    int sbase = k * SREG;
    crow[t] = cnts[k * 256 + t];
    deg[t] = 0;
    __syncthreads();
    // deg count over slot space (skip empty slot tails)
    for (int i = t; i < SREG; i += 256) {
        int b = i / SLOT, j = i - b * SLOT;
        if (j < crow[b])
            atomicAdd(&deg[staged[sbase + i] & 255], 1);
    }
    __syncthreads();
    int v = deg[t];
    sc[t] = v;
    __syncthreads();
#pragma unroll
    for (int d = 1; d < 256; d <<= 1) {
        int u = (t >= d) ? sc[t - d] : 0;
        __syncthreads();
        sc[t] += u;
        __syncthreads();
    }
    int start = sc[t] - v;
    int cnt = sc[255];                      // total edges in bucket
    int node = k * 256 + t;
    if (node < N_NODES) {
        startA[node] = k * CCAP + start;
        endA[node]   = k * CCAP + start + v;
    }
    curs[t] = start;
    __syncthreads();
    for (int i = t; i < SREG; i += 256) {
        int b = i / SLOT, j = i - b * SLOT;
        if (j < crow[b]) {
            int e = staged[sbase + i];
            int pos = atomicAdd(&curs[e & 255], 1);
            lcsr[pos] = e >> 8;             // LDS scatter (fast)
        }
    }
    __syncthreads();
    for (int i = t; i < cnt; i += 256)      // coalesced flush
        csr[k * CCAP + i] = lcsr[i];
}

// ---------- dual-output GEMM body: R = X@Wr (fp32), Nn = X@Wn (bf16) --------
template<int XBF>
__device__ __forceinline__ void gemm_body(
    const float* __restrict__ Xf, const unsigned short* __restrict__ Xb,
    const float* __restrict__ Wr, const float* __restrict__ Wn,
    float* __restrict__ outR, unsigned short* __restrict__ outN,
    int node0, int tid, char* smem) {
    float (*sXT)[D] = (float(*)[D])smem;             // 16 KB
    float (*sWr)[D] = (float(*)[D])(smem + 16384);   // 16 KB
    float (*sWn)[D] = (float(*)[D])(smem + 32768);   // 16 KB

#pragma unroll
    for (int i = 0; i < 4; i++) {
        int idx = tid + 256 * i;
        ((float4*)sWr)[idx] = ((const float4*)Wr)[idx];
        ((float4*)sWn)[idx] = ((const float4*)Wn)[idx];
    }
    int nd = tid & 63;
    int gn = min(node0 + nd, N_NODES - 1);
    if (XBF) {
#pragma unroll
        for (int pass = 0; pass < 2; pass++) {
            int kg = (tid >> 6) + pass * 4;       // 0..7
            int k0 = kg * 8;
            uint4 ux = *(const uint4*)(Xb + (size_t)gn * D + k0);
            sXT[k0 + 0][nd] = bflo(ux.x); sXT[k0 + 1][nd] = bfhi(ux.x);
            sXT[k0 + 2][nd] = bflo(ux.y); sXT[k0 + 3][nd] = bfhi(ux.y);
            sXT[k0 + 4][nd] = bflo(ux.z); sXT[k0 + 5][nd] = bfhi(ux.z);
            sXT[k0 + 6][nd] = bflo(ux.w); sXT[k0 + 7][nd] = bfhi(ux.w);
        }
    } else {
        const float4* X4 = (const float4*)Xf;
#pragma unroll
        for (int pass = 0; pass < 4; pass++) {
            int kq = (tid >> 6) + pass * 4;
            float4 v = X4[gn * 16 + kq];
            sXT[kq * 4 + 0][nd] = v.x; sXT[kq * 4 + 1][nd] = v.y;
            sXT[kq * 4 + 2][nd] = v.z; sXT[kq * 4 + 3][nd] = v.w;
        }
    }
    __syncthreads();

    int nq = tid >> 4;
    int cq = tid & 15;
    float accR[4][4];
    float accN[4][4];
#pragma unroll
    for (int i = 0; i < 4; i++)
#pragma unroll
        for (int jj = 0; jj < 4; jj++) { accR[i][jj] = 0.f; accN[i][jj] = 0.f; }

#pragma unroll 16
    for (int k = 0; k < D; k++) {
        float4 xv = *(const float4*)&sXT[k][nq * 4];
        float4 wr = *(const float4*)&sWr[k][cq * 4];
        float4 wn = *(const float4*)&sWn[k][cq * 4];
        float xs[4] = {xv.x, xv.y, xv.z, xv.w};
        float rs[4] = {wr.x, wr.y, wr.z, wr.w};
        float ns[4] = {wn.x, wn.y, wn.z, wn.w};
#pragma unroll
        for (int i = 0; i < 4; i++)
#pragma unroll
            for (int jj = 0; jj < 4; jj++) {
                accR[i][jj] = fmaf(xs[i], rs[jj], accR[i][jj]);
                accN[i][jj] = fmaf(xs[i], ns[jj], accN[i][jj]);
            }
    }

    float4* outR4 = (float4*)outR;
#pragma unroll
    for (int i = 0; i < 4; i++) {
        int node = node0 + nq * 4 + i;
        if (node < N_NODES) {
            float4 r;
            r.x = accR[i][0]; r.y = accR[i][1];
            r.z = accR[i][2]; r.w = accR[i][3];
            outR4[node * 16 + cq] = r;
            ushort4 rb;
            rb.x = f2bf(accN[i][0]); rb.y = f2bf(accN[i][1]);
            rb.z = f2bf(accN[i][2]); rb.w = f2bf(accN[i][3]);
            *(ushort4*)(outN + (size_t)node * D + cq * 4) = rb;
        }
    }
}

// ---------- merged scatter + layer-1 GEMM (block-specialized) ---------------
__global__ void __launch_bounds__(256) scatter_gemm1(
    const int* __restrict__ src, const int* __restrict__ dst,
    int* __restrict__ cnts, int* __restrict__ staged,
    const float* __restrict__ X,
    const float* __restrict__ Wr, const float* __restrict__ Wn,
    float* __restrict__ xr, unsigned short* __restrict__ xn) {
    __shared__ char smem[49152];
    if (blockIdx.x < SBLOCKS) {
        scatter_body(src, dst, cnts, staged, smem, blockIdx.x, threadIdx.x);
    } else {
        gemm_body<0>(X, (const unsigned short*)0, Wr, Wn, xr, xn,
                     (blockIdx.x - SBLOCKS) * 64, threadIdx.x, smem);
    }
}

__global__ void __launch_bounds__(256) csr_build_kernel(
    const int* __restrict__ cnts, const int* __restrict__ staged,
    int* __restrict__ csr, int* __restrict__ startA, int* __restrict__ endA) {
    __shared__ char smem[4096 + CCAP * 4];
    csr_body(cnts, staged, csr, startA, endA, smem, blockIdx.x, threadIdx.x);
}

// ---------- standalone layer-2 GEMM (bf16 input) ----------------------------
__global__ void __launch_bounds__(256) gemm2(
    const unsigned short* __restrict__ Xb,
    const float* __restrict__ Wr, const float* __restrict__ Wn,
    float* __restrict__ hr, unsigned short* __restrict__ hn) {
    __shared__ char smem[49152];
    gemm_body<1>((const float*)0, Xb, Wr, Wn, hr, hn,
                 blockIdx.x * 64, threadIdx.x, smem);
}

// ---------- Gather (uint4 / 8-lane-row-group) + fused epilogue --------------
template<int RELU, int OUTBF>
__global__ void __launch_bounds__(256) gather_fused(
    const unsigned short* __restrict__ Gsrc, const float* __restrict__ Root,
    const float* __restrict__ bias,
    const int* __restrict__ startA, const int* __restrict__ endA,
    const int* __restrict__ csr,
    float* __restrict__ outF, unsigned short* __restrict__ outB) {
    int tid = threadIdx.x;
    int wave = tid >> 6, lane = tid & 63;
    int node = blockIdx.x * 4 + wave;
    int sub = lane >> 3, fq = lane & 7;
    int j0 = startA[node], je = endA[node];
    float a0=0.f,a1=0.f,a2=0.f,a3=0.f,a4=0.f,a5=0.f,a6=0.f,a7=0.f;
    for (int jb = j0; jb < je; jb += 64) {          // je wave-uniform
        int idx = jb + lane;
        int p = csr[idx < je ? idx : (je - 1)];     // coalesced index batch
        int m = min(64, je - jb);                   // wave-uniform
        int b = 0;
        for (; b + 16 <= m; b += 16) {
            int i0 = __shfl(p, b + sub, 64);
            int i1 = __shfl(p, b + 8 + sub, 64);
            uint4 u0 = *(const uint4*)(Gsrc + i0 * D + fq * 8);
            uint4 u1 = *(const uint4*)(Gsrc + i1 * D + fq * 8);
            a0 += bflo(u0.x) + bflo(u1.x);  a1 += bfhi(u0.x) + bfhi(u1.x);
            a2 += bflo(u0.y) + bflo(u1.y);  a3 += bfhi(u0.y) + bfhi(u1.y);
            a4 += bflo(u0.z) + bflo(u1.z);  a5 += bfhi(u0.z) + bfhi(u1.z);
            a6 += bflo(u0.w) + bflo(u1.w);  a7 += bfhi(u0.w) + bfhi(u1.w);
        }
        for (; b < m; b += 8) {                     // uniform condition
            int sidx = b + sub;
            int scl = sidx < m ? sidx : (m - 1);    // active source lane
            int i0 = __shfl(p, scl, 64);            // executed by ALL lanes
            if (sidx < m) {                         // divergence only here
                uint4 u = *(const uint4*)(Gsrc + i0 * D + fq * 8);
                a0 += bflo(u.x); a1 += bfhi(u.x);
                a2 += bflo(u.y); a3 += bfhi(u.y);
                a4 += bflo(u.z); a5 += bfhi(u.z);
                a6 += bflo(u.w); a7 += bfhi(u.w);
            }
        }
    }
#pragma unroll
    for (int mk = 8; mk <= 32; mk <<= 1) {
        a0 += __shfl_xor(a0, mk, 64); a1 += __shfl_xor(a1, mk, 64);
        a2 += __shfl_xor(a2, mk, 64); a3 += __shfl_xor(a3, mk, 64);
        a4 += __shfl_xor(a4, mk, 64); a5 += __shfl_xor(a5, mk, 64);
        a6 += __shfl_xor(a6, mk, 64); a7 += __shfl_xor(a7, mk, 64);
    }
    if (sub == 0) {
        const float* rp = Root + (size_t)node * D + fq * 8;
        float4 x0 = *(const float4*)rp;
        float4 x1 = *(const float4*)(rp + 4);
        float4 b0 = ((const float4*)bias)[fq * 2];
        float4 b1 = ((const float4*)bias)[fq * 2 + 1];
        float r0 = a0 + x0.x + b0.x, r1 = a1 + x0.y + b0.y;
        float r2 = a2 + x0.z + b0.z, r3 = a3 + x0.w + b0.w;
        float r4 = a4 + x1.x + b1.x, r5 = a5 + x1.y + b1.y;
        float r6 = a6 + x1.z + b1.z, r7 = a7 + x1.w + b1.w;
        if (RELU) {
            r0 = fmaxf(r0, 0.f); r1 = fmaxf(r1, 0.f);
            r2 = fmaxf(r2, 0.f); r3 = fmaxf(r3, 0.f);
            r4 = fmaxf(r4, 0.f); r5 = fmaxf(r5, 0.f);
            r6 = fmaxf(r6, 0.f); r7 = fmaxf(r7, 0.f);
        }
        if (OUTBF) {
            uint4 u;
            u.x = (unsigned)f2bf(r0) | ((unsigned)f2bf(r1) << 16);
            u.y = (unsigned)f2bf(r2) | ((unsigned)f2bf(r3) << 16);
            u.z = (unsigned)f2bf(r4) | ((unsigned)f2bf(r5) << 16);
            u.w = (unsigned)f2bf(r6) | ((unsigned)f2bf(r7) << 16);
            *(uint4*)(outB + (size_t)node * D + fq * 8) = u;
        } else {
            float4 w0; w0.x = r0; w0.y = r1; w0.z = r2; w0.w = r3;
            float4 w1; w1.x = r4; w1.y = r5; w1.z = r6; w1.w = r7;
            *(float4*)(outF + (size_t)node * D + fq * 8) = w0;
            *(float4*)(outF + (size_t)node * D + fq * 8 + 4) = w1;
        }
    }
}

// ---------- launch ----------------------------------------------------------
extern "C" void kernel_launch(void* const* d_in, const int* in_sizes, int n_in,
                              void* d_out, int out_size, void* d_ws, size_t ws_size,
                              hipStream_t stream) {
    const float* x   = (const float*)d_in[0];
    const int*   edg = (const int*)d_in[1];
    const float* W1r = (const float*)d_in[2];
    const float* W1n = (const float*)d_in[3];
    const float* b1  = (const float*)d_in[4];
    const float* W2r = (const float*)d_in[5];
    const float* W2n = (const float*)d_in[6];
    const float* b2  = (const float*)d_in[7];
    float* out = (float*)d_out;

    const int* src = edg;
    const int* dst = edg + N_EDGES;

    // ws (256 MiB) — non-overlapping layout. cnts fully overwritten each
    // iteration by scatter; no memset needed anywhere.
    int* W              = (int*)d_ws;
    int* cnts           = W;                          // NBUCKETS*256 ints
    int* staged         = W + NBUCKETS * 256;         // NBUCKETS*SREG ints
    int* csr            = staged + NBUCKETS * SREG;   // NBUCKETS*CCAP ints
    int* startA         = csr + NBUCKETS * CCAP;
    int* endA           = startA + N_NODES;
    float* xr           = (float*)(endA + N_NODES);   // fp32 [N][64] root L1
    unsigned short* xn  = (unsigned short*)(xr + (size_t)N_NODES * D); // bf16 x@W1n
    unsigned short* hbf = xn + (size_t)N_NODES * D;   // bf16 h
    float* hr           = (float*)(hbf + (size_t)N_NODES * D);         // fp32 h@W2r
    unsigned short* hn  = (unsigned short*)(hr + (size_t)N_NODES * D); // bf16 h@W2n

    // [scatter || layer-1 dual GEMM]  (xr = x@W1r fp32, xn = x@W1n bf16)
    scatter_gemm1<<<SBLOCKS + MB, 256, 0, stream>>>(
        src, dst, cnts, staged, x, W1r, W1n, xr, xn);

    csr_build_kernel<<<NBUCKETS, 256, 0, stream>>>(cnts, staged, csr,
                                                   startA, endA);

    const int GB = N_NODES / 4;          // 12500

    // h = relu(xr + segsum(xn[src]) + b1), written bf16.
    gather_fused<1, 1><<<GB, 256, 0, stream>>>(
        xn, xr, b1, startA, endA, csr, (float*)0, hbf);

    // layer-2 dual GEMM: hr = h@W2r fp32, hn = h@W2n bf16.
    gemm2<<<MB, 256, 0, stream>>>(hbf, W2r, W2n, hr, hn);

    // out = hr + segsum(hn[src]) + b2, written fp32.
    gather_fused<0, 0><<<GB, 256, 0, stream>>>(
        hn, hr, b2, startA, endA, csr, out, (unsigned short*)0);
}

// Round 6
// 175.351 us; speedup vs baseline: 1.8210x; 1.0495x over previous
//
#include <hip/hip_runtime.h>

#define N_NODES 50000
#define N_EDGES 800000
#define D 64
#define NBUCKETS 782          // dst>>6, 0..781
#define NPB 64                // nodes per bucket
#define BCAP 2048             // per-bucket capacity (Poisson(1024), huge margin)
#define SBLOCKS 256           // scatter blocks
#define CHUNK (N_EDGES / SBLOCKS)   // 3125
#define MB ((N_NODES + 63) / 64)    // 782 gemm tiles

// bf16 helpers (RNE), bit-level.
__device__ __forceinline__ unsigned short f2bf(float f) {
    unsigned u = __float_as_uint(f);
    return (unsigned short)((u + 0x7fffu + ((u >> 16) & 1u)) >> 16);
}
__device__ __forceinline__ float bflo(unsigned u) {
    return __uint_as_float(u << 16);
}
__device__ __forceinline__ float bfhi(unsigned u) {
    return __uint_as_float(u & 0xffff0000u);
}

// ---------- scatter body (verified R3 two-pass form; fine buckets) ----------
// LDS layout within smem: hist@0 (782 ints), curs@3200 (782 ints),
// pk@6400 (3125 ints), bk@18900 (3125 u16). Total ~25.2 KB.
__device__ __forceinline__ void scatter_body(
    const int* __restrict__ src, const int* __restrict__ dst,
    int* __restrict__ cursorPad, int* __restrict__ staged,
    char* smem, int bid, int t) {
    int* hist = (int*)smem;
    int* curs = (int*)(smem + 3200);
    int* pk   = (int*)(smem + 6400);
    unsigned short* bk = (unsigned short*)(smem + 6400 + 12500);
    for (int i = t; i < NBUCKETS; i += 256) hist[i] = 0;
    __syncthreads();
    int lo = bid * CHUNK;
    for (int i = t; i < CHUNK; i += 256) {
        int d = dst[lo + i];
        int s = src[lo + i];
        pk[i] = (s << 6) | (d & 63);
        bk[i] = (unsigned short)(d >> 6);
        atomicAdd(&hist[d >> 6], 1);
    }
    __syncthreads();
    for (int k = t; k < NBUCKETS; k += 256)
        if (hist[k] > 0)
            curs[k] = k * BCAP + atomicAdd(&cursorPad[k * 16], hist[k]);
    __syncthreads();
    for (int i = t; i < CHUNK; i += 256) {
        int b = bk[i];
        int pos = atomicAdd(&curs[b], 1);
        staged[pos] = pk[i];
    }
}

// ---------- per-bucket CSR build (fine buckets: 64 nodes, ~1024 edges) ------
// 782 blocks -> ~3 blocks/CU (vs 196 -> 1) for latency hiding; 6-step scan.
__global__ void __launch_bounds__(256) csr_build_kernel(
    const int* __restrict__ cursorPad, const int* __restrict__ staged,
    int* __restrict__ csr, int* __restrict__ startA, int* __restrict__ endA) {
    __shared__ int deg[NPB];
    __shared__ int sc[NPB];
    __shared__ int curs[NPB];
    __shared__ int lcsr[BCAP];      // 8 KB image
    int k = blockIdx.x;
    int t = threadIdx.x;
    int base = k * BCAP;
    int cnt  = cursorPad[k * 16];
    if (t < NPB) deg[t] = 0;
    __syncthreads();
    for (int i = t; i < cnt; i += 256)
        atomicAdd(&deg[staged[base + i] & 63], 1);
    __syncthreads();
    int v = (t < NPB) ? deg[t] : 0;
    if (t < NPB) sc[t] = v;
    __syncthreads();
#pragma unroll
    for (int d = 1; d < NPB; d <<= 1) {
        int u = (t < NPB && t >= d) ? sc[t - d] : 0;
        __syncthreads();
        if (t < NPB) sc[t] += u;
        __syncthreads();
    }
    if (t < NPB) {
        int start = sc[t] - v;
        int node = k * NPB + t;
        if (node < N_NODES) {
            startA[node] = base + start;
            endA[node]   = base + start + v;
        }
        curs[t] = start;
    }
    __syncthreads();
    for (int i = t; i < cnt; i += 256) {
        int e = staged[base + i];
        int pos = atomicAdd(&curs[e & 63], 1);
        lcsr[pos] = e >> 6;                 // LDS scatter (fast)
    }
    __syncthreads();
    for (int i = t; i < cnt; i += 256)      // coalesced flush
        csr[base + i] = lcsr[i];
}

// ---------- dual-output GEMM body: R = X@Wr (fp32), Nn = X@Wn (bf16) --------
template<int XBF>
__device__ __forceinline__ void gemm_body(
    const float* __restrict__ Xf, const unsigned short* __restrict__ Xb,
    const float* __restrict__ Wr, const float* __restrict__ Wn,
    float* __restrict__ outR, unsigned short* __restrict__ outN,
    int node0, int tid, char* smem) {
    float (*sXT)[D] = (float(*)[D])smem;             // 16 KB
    float (*sWr)[D] = (float(*)[D])(smem + 16384);   // 16 KB
    float (*sWn)[D] = (float(*)[D])(smem + 32768);   // 16 KB

#pragma unroll
    for (int i = 0; i < 4; i++) {
        int idx = tid + 256 * i;
        ((float4*)sWr)[idx] = ((const float4*)Wr)[idx];
        ((float4*)sWn)[idx] = ((const float4*)Wn)[idx];
    }
    int nd = tid & 63;
    int gn = min(node0 + nd, N_NODES - 1);
    if (XBF) {
#pragma unroll
        for (int pass = 0; pass < 2; pass++) {
            int kg = (tid >> 6) + pass * 4;       // 0..7
            int k0 = kg * 8;
            uint4 ux = *(const uint4*)(Xb + (size_t)gn * D + k0);
            sXT[k0 + 0][nd] = bflo(ux.x); sXT[k0 + 1][nd] = bfhi(ux.x);
            sXT[k0 + 2][nd] = bflo(ux.y); sXT[k0 + 3][nd] = bfhi(ux.y);
            sXT[k0 + 4][nd] = bflo(ux.z); sXT[k0 + 5][nd] = bfhi(ux.z);
            sXT[k0 + 6][nd] = bflo(ux.w); sXT[k0 + 7][nd] = bfhi(ux.w);
        }
    } else {
        const float4* X4 = (const float4*)Xf;
#pragma unroll
        for (int pass = 0; pass < 4; pass++) {
            int kq = (tid >> 6) + pass * 4;
            float4 v = X4[gn * 16 + kq];
            sXT[kq * 4 + 0][nd] = v.x; sXT[kq * 4 + 1][nd] = v.y;
            sXT[kq * 4 + 2][nd] = v.z; sXT[kq * 4 + 3][nd] = v.w;
        }
    }
    __syncthreads();

    int nq = tid >> 4;
    int cq = tid & 15;
    float accR[4][4];
    float accN[4][4];
#pragma unroll
    for (int i = 0; i < 4; i++)
#pragma unroll
        for (int jj = 0; jj < 4; jj++) { accR[i][jj] = 0.f; accN[i][jj] = 0.f; }

#pragma unroll 16
    for (int k = 0; k < D; k++) {
        float4 xv = *(const float4*)&sXT[k][nq * 4];
        float4 wr = *(const float4*)&sWr[k][cq * 4];
        float4 wn = *(const float4*)&sWn[k][cq * 4];
        float xs[4] = {xv.x, xv.y, xv.z, xv.w};
        float rs[4] = {wr.x, wr.y, wr.z, wr.w};
        float ns[4] = {wn.x, wn.y, wn.z, wn.w};
#pragma unroll
        for (int i = 0; i < 4; i++)
#pragma unroll
            for (int jj = 0; jj < 4; jj++) {
                accR[i][jj] = fmaf(xs[i], rs[jj], accR[i][jj]);
                accN[i][jj] = fmaf(xs[i], ns[jj], accN[i][jj]);
            }
    }

    float4* outR4 = (float4*)outR;
#pragma unroll
    for (int i = 0; i < 4; i++) {
        int node = node0 + nq * 4 + i;
        if (node < N_NODES) {
            float4 r;
            r.x = accR[i][0]; r.y = accR[i][1];
            r.z = accR[i][2]; r.w = accR[i][3];
            outR4[node * 16 + cq] = r;
            ushort4 rb;
            rb.x = f2bf(accN[i][0]); rb.y = f2bf(accN[i][1]);
            rb.z = f2bf(accN[i][2]); rb.w = f2bf(accN[i][3]);
            *(ushort4*)(outN + (size_t)node * D + cq * 4) = rb;
        }
    }
}

// ---------- merged scatter + layer-1 GEMM (block-specialized) ---------------
__global__ void __launch_bounds__(256) scatter_gemm1(
    const int* __restrict__ src, const int* __restrict__ dst,
    int* __restrict__ cursorPad, int* __restrict__ staged,
    const float* __restrict__ X,
    const float* __restrict__ Wr, const float* __restrict__ Wn,
    float* __restrict__ xr, unsigned short* __restrict__ xn) {
    __shared__ char smem[49152];
    if (blockIdx.x < SBLOCKS) {
        scatter_body(src, dst, cursorPad, staged, smem, blockIdx.x, threadIdx.x);
    } else {
        gemm_body<0>(X, (const unsigned short*)0, Wr, Wn, xr, xn,
                     (blockIdx.x - SBLOCKS) * 64, threadIdx.x, smem);
    }
}

// ---------- standalone layer-2 GEMM (bf16 input) ----------------------------
__global__ void __launch_bounds__(256) gemm2(
    const unsigned short* __restrict__ Xb,
    const float* __restrict__ Wr, const float* __restrict__ Wn,
    float* __restrict__ hr, unsigned short* __restrict__ hn) {
    __shared__ char smem[49152];
    gemm_body<1>((const float*)0, Xb, Wr, Wn, hr, hn,
                 blockIdx.x * 64, threadIdx.x, smem);
}

// ---------- Gather (uint4 / 8-lane-row-group) + fused epilogue --------------
template<int RELU, int OUTBF>
__global__ void __launch_bounds__(256) gather_fused(
    const unsigned short* __restrict__ Gsrc, const float* __restrict__ Root,
    const float* __restrict__ bias,
    const int* __restrict__ startA, const int* __restrict__ endA,
    const int* __restrict__ csr,
    float* __restrict__ outF, unsigned short* __restrict__ outB) {
    int tid = threadIdx.x;
    int wave = tid >> 6, lane = tid & 63;
    int node = blockIdx.x * 4 + wave;
    int sub = lane >> 3, fq = lane & 7;
    int j0 = startA[node], je = endA[node];
    float a0=0.f,a1=0.f,a2=0.f,a3=0.f,a4=0.f,a5=0.f,a6=0.f,a7=0.f;
    for (int jb = j0; jb < je; jb += 64) {          // je wave-uniform
        int idx = jb + lane;
        int p = csr[idx < je ? idx : (je - 1)];     // coalesced index batch
        int m = min(64, je - jb);                   // wave-uniform
        int b = 0;
        for (; b + 16 <= m; b += 16) {
            int i0 = __shfl(p, b + sub, 64);
            int i1 = __shfl(p, b + 8 + sub, 64);
            uint4 u0 = *(const uint4*)(Gsrc + i0 * D + fq * 8);
            uint4 u1 = *(const uint4*)(Gsrc + i1 * D + fq * 8);
            a0 += bflo(u0.x) + bflo(u1.x);  a1 += bfhi(u0.x) + bfhi(u1.x);
            a2 += bflo(u0.y) + bflo(u1.y);  a3 += bfhi(u0.y) + bfhi(u1.y);
            a4 += bflo(u0.z) + bflo(u1.z);  a5 += bfhi(u0.z) + bfhi(u1.z);
            a6 += bflo(u0.w) + bflo(u1.w);  a7 += bfhi(u0.w) + bfhi(u1.w);
        }
        for (; b < m; b += 8) {                     // uniform condition
            int sidx = b + sub;
            int scl = sidx < m ? sidx : (m - 1);    // active source lane
            int i0 = __shfl(p, scl, 64);            // executed by ALL lanes
            if (sidx < m) {                         // divergence only here
                uint4 u = *(const uint4*)(Gsrc + i0 * D + fq * 8);
                a0 += bflo(u.x); a1 += bfhi(u.x);
                a2 += bflo(u.y); a3 += bfhi(u.y);
                a4 += bflo(u.z); a5 += bfhi(u.z);
                a6 += bflo(u.w); a7 += bfhi(u.w);
            }
        }
    }
#pragma unroll
    for (int mk = 8; mk <= 32; mk <<= 1) {
        a0 += __shfl_xor(a0, mk, 64); a1 += __shfl_xor(a1, mk, 64);
        a2 += __shfl_xor(a2, mk, 64); a3 += __shfl_xor(a3, mk, 64);
        a4 += __shfl_xor(a4, mk, 64); a5 += __shfl_xor(a5, mk, 64);
        a6 += __shfl_xor(a6, mk, 64); a7 += __shfl_xor(a7, mk, 64);
    }
    if (sub == 0) {
        const float* rp = Root + (size_t)node * D + fq * 8;
        float4 x0 = *(const float4*)rp;
        float4 x1 = *(const float4*)(rp + 4);
        float4 b0 = ((const float4*)bias)[fq * 2];
        float4 b1 = ((const float4*)bias)[fq * 2 + 1];
        float r0 = a0 + x0.x + b0.x, r1 = a1 + x0.y + b0.y;
        float r2 = a2 + x0.z + b0.z, r3 = a3 + x0.w + b0.w;
        float r4 = a4 + x1.x + b1.x, r5 = a5 + x1.y + b1.y;
        float r6 = a6 + x1.z + b1.z, r7 = a7 + x1.w + b1.w;
        if (RELU) {
            r0 = fmaxf(r0, 0.f); r1 = fmaxf(r1, 0.f);
            r2 = fmaxf(r2, 0.f); r3 = fmaxf(r3, 0.f);
            r4 = fmaxf(r4, 0.f); r5 = fmaxf(r5, 0.f);
            r6 = fmaxf(r6, 0.f); r7 = fmaxf(r7, 0.f);
        }
        if (OUTBF) {
            uint4 u;
            u.x = (unsigned)f2bf(r0) | ((unsigned)f2bf(r1) << 16);
            u.y = (unsigned)f2bf(r2) | ((unsigned)f2bf(r3) << 16);
            u.z = (unsigned)f2bf(r4) | ((unsigned)f2bf(r5) << 16);
            u.w = (unsigned)f2bf(r6) | ((unsigned)f2bf(r7) << 16);
            *(uint4*)(outB + (size_t)node * D + fq * 8) = u;
        } else {
            float4 w0; w0.x = r0; w0.y = r1; w0.z = r2; w0.w = r3;
            float4 w1; w1.x = r4; w1.y = r5; w1.z = r6; w1.w = r7;
            *(float4*)(outF + (size_t)node * D + fq * 8) = w0;
            *(float4*)(outF + (size_t)node * D + fq * 8 + 4) = w1;
        }
    }
}

// ---------- launch ----------------------------------------------------------
extern "C" void kernel_launch(void* const* d_in, const int* in_sizes, int n_in,
                              void* d_out, int out_size, void* d_ws, size_t ws_size,
                              hipStream_t stream) {
    const float* x   = (const float*)d_in[0];
    const int*   edg = (const int*)d_in[1];
    const float* W1r = (const float*)d_in[2];
    const float* W1n = (const float*)d_in[3];
    const float* b1  = (const float*)d_in[4];
    const float* W2r = (const float*)d_in[5];
    const float* W2n = (const float*)d_in[6];
    const float* b2  = (const float*)d_in[7];
    float* out = (float*)d_out;

    const int* src = edg;
    const int* dst = edg + N_EDGES;

    // ws (256 MiB) — non-overlapping layout.
    int* W              = (int*)d_ws;
    int* cursorPad      = W;                          // NBUCKETS*16 ints
    int* staged         = W + NBUCKETS * 16;          // NBUCKETS*BCAP ints
    int* csr            = staged + NBUCKETS * BCAP;   // NBUCKETS*BCAP ints
    int* startA         = csr + NBUCKETS * BCAP;
    int* endA           = startA + N_NODES;
    float* xr           = (float*)(endA + N_NODES);   // fp32 [N][64] root L1
    unsigned short* xn  = (unsigned short*)(xr + (size_t)N_NODES * D); // bf16 x@W1n
    unsigned short* hbf = xn + (size_t)N_NODES * D;   // bf16 h
    float* hr           = (float*)(hbf + (size_t)N_NODES * D);         // fp32 h@W2r
    unsigned short* hn  = (unsigned short*)(hr + (size_t)N_NODES * D); // bf16 h@W2n

    hipMemsetAsync(cursorPad, 0, NBUCKETS * 16 * sizeof(int), stream);

    // [scatter || layer-1 dual GEMM]  (xr = x@W1r fp32, xn = x@W1n bf16)
    scatter_gemm1<<<SBLOCKS + MB, 256, 0, stream>>>(
        src, dst, cursorPad, staged, x, W1r, W1n, xr, xn);

    csr_build_kernel<<<NBUCKETS, 256, 0, stream>>>(cursorPad, staged, csr,
                                                   startA, endA);

    const int GB = N_NODES / 4;          // 12500

    // h = relu(xr + segsum(xn[src]) + b1), written bf16.
    gather_fused<1, 1><<<GB, 256, 0, stream>>>(
        xn, xr, b1, startA, endA, csr, (float*)0, hbf);

    // layer-2 dual GEMM: hr = h@W2r fp32, hn = h@W2n bf16.
    gemm2<<<MB, 256, 0, stream>>>(hbf, W2r, W2n, hr, hn);

    // out = hr + segsum(hn[src]) + b2, written fp32.
    gather_fused<0, 0><<<GB, 256, 0, stream>>>(
        hn, hr, b2, startA, endA, csr, out, (unsigned short*)0);
}

// Round 7
// 173.368 us; speedup vs baseline: 1.8418x; 1.0114x over previous
//
#include <hip/hip_runtime.h>

#define N_NODES 50000
#define N_EDGES 800000
#define D 64
#define NBUCKETS 782          // dst>>6, 0..781
#define NPB 64                // nodes per bucket
#define BCAP 2048             // per-bucket capacity (Poisson(1024), huge margin)
#define SBLOCKS 256           // scatter blocks
#define CHUNK (N_EDGES / SBLOCKS)   // 3125
#define MB ((N_NODES + 63) / 64)    // 782 gemm tiles

typedef short bf16x8 __attribute__((ext_vector_type(8)));   // 8 bf16 = 4 VGPRs
typedef float f32x4  __attribute__((ext_vector_type(4)));   // MFMA accumulator

// bf16 helpers (RNE), bit-level.
__device__ __forceinline__ unsigned short f2bf(float f) {
    unsigned u = __float_as_uint(f);
    return (unsigned short)((u + 0x7fffu + ((u >> 16) & 1u)) >> 16);
}
__device__ __forceinline__ float bflo(unsigned u) {
    return __uint_as_float(u << 16);
}
__device__ __forceinline__ float bfhi(unsigned u) {
    return __uint_as_float(u & 0xffff0000u);
}

// ---------- prep: zero cursors + build bf16 W^T for all 4 weights -----------
// Replaces the memset dispatch. wt[m][c][k] = bf16(W_m[k][c]).
__global__ void __launch_bounds__(256) prep_kernel(
    const float* __restrict__ W1r, const float* __restrict__ W1n,
    const float* __restrict__ W2r, const float* __restrict__ W2n,
    int* __restrict__ cursorPad, unsigned short* __restrict__ wt) {
    int t = threadIdx.x;
    if (blockIdx.x == 4) {
        for (int i = t; i < NBUCKETS * 16; i += 256) cursorPad[i] = 0;
        return;
    }
    const float* Wsrc = blockIdx.x == 0 ? W1r : blockIdx.x == 1 ? W1n
                      : blockIdx.x == 2 ? W2r : W2n;
    unsigned short* dstw = wt + blockIdx.x * D * D;
    for (int i = t; i < D * D; i += 256) {
        int k = i >> 6, c = i & 63;           // coalesced read of W[k][c]
        dstw[c * D + k] = f2bf(Wsrc[i]);      // transposed bf16 store
    }
}

// ---------- scatter body (verified R3 two-pass form; fine buckets) ----------
__device__ __forceinline__ void scatter_body(
    const int* __restrict__ src, const int* __restrict__ dst,
    int* __restrict__ cursorPad, int* __restrict__ staged,
    char* smem, int bid, int t) {
    int* hist = (int*)smem;
    int* curs = (int*)(smem + 3200);
    int* pk   = (int*)(smem + 6400);
    unsigned short* bk = (unsigned short*)(smem + 6400 + 12500);
    for (int i = t; i < NBUCKETS; i += 256) hist[i] = 0;
    __syncthreads();
    int lo = bid * CHUNK;
    for (int i = t; i < CHUNK; i += 256) {
        int d = dst[lo + i];
        int s = src[lo + i];
        pk[i] = (s << 6) | (d & 63);
        bk[i] = (unsigned short)(d >> 6);
        atomicAdd(&hist[d >> 6], 1);
    }
    __syncthreads();
    for (int k = t; k < NBUCKETS; k += 256)
        if (hist[k] > 0)
            curs[k] = k * BCAP + atomicAdd(&cursorPad[k * 16], hist[k]);
    __syncthreads();
    for (int i = t; i < CHUNK; i += 256) {
        int b = bk[i];
        int pos = atomicAdd(&curs[b], 1);
        staged[pos] = pk[i];
    }
}

// ---------- MFMA dual GEMM body: R = X@Wr (fp32 out), N = X@Wn (bf16 out) ---
// Fragments per the m89/m91-verified gfx950 layouts:
//   operand frag (both A and B): lane l holds row (l&15), k = (l>>4)*8 + j
//   D = A·B^T : D[i][j] = sum_k Arow_i[k]*Brow_j[k]
//   C/D: col = lane&15, row = (lane>>4)*4 + reg
// B operand = rows of W^T (i.e. columns of W) from the prep kernel's wt.
template<int XBF>
__device__ __forceinline__ void gemm_mfma_body(
    const float* __restrict__ Xf, const unsigned short* __restrict__ Xb,
    const unsigned short* __restrict__ Wtr, const unsigned short* __restrict__ Wtn,
    float* __restrict__ outR, unsigned short* __restrict__ outN,
    int node0, int tid) {
    int wave = tid >> 6, lane = tid & 63;
    int rbase = node0 + wave * 16;            // 16 nodes per wave
    int rrow  = lane & 15;
    int kg    = lane >> 4;                    // k-chunk selector (0..3)
    int row   = min(rbase + rrow, N_NODES - 1);

    bf16x8 a0, a1;                            // k 0..31 / 32..63
    if (XBF) {
        a0 = *(const bf16x8*)(Xb + (size_t)row * D + kg * 8);
        a1 = *(const bf16x8*)(Xb + (size_t)row * D + 32 + kg * 8);
    } else {
        const float* xp = Xf + (size_t)row * D + kg * 8;
#pragma unroll
        for (int j = 0; j < 8; j++) a0[j] = (short)f2bf(xp[j]);
#pragma unroll
        for (int j = 0; j < 8; j++) a1[j] = (short)f2bf(xp[32 + j]);
    }

    f32x4 accR[4], accN[4];
#pragma unroll
    for (int t = 0; t < 4; t++) {
        accR[t][0] = 0.f; accR[t][1] = 0.f; accR[t][2] = 0.f; accR[t][3] = 0.f;
        accN[t][0] = 0.f; accN[t][1] = 0.f; accN[t][2] = 0.f; accN[t][3] = 0.f;
    }

#pragma unroll
    for (int t = 0; t < 4; t++) {
        int c = t * 16 + rrow;                // W^T row = W column
        bf16x8 br0 = *(const bf16x8*)(Wtr + c * D + kg * 8);
        bf16x8 br1 = *(const bf16x8*)(Wtr + c * D + 32 + kg * 8);
        bf16x8 bn0 = *(const bf16x8*)(Wtn + c * D + kg * 8);
        bf16x8 bn1 = *(const bf16x8*)(Wtn + c * D + 32 + kg * 8);
        accR[t] = __builtin_amdgcn_mfma_f32_16x16x32_bf16(a0, br0, accR[t], 0, 0, 0);
        accR[t] = __builtin_amdgcn_mfma_f32_16x16x32_bf16(a1, br1, accR[t], 0, 0, 0);
        accN[t] = __builtin_amdgcn_mfma_f32_16x16x32_bf16(a0, bn0, accN[t], 0, 0, 0);
        accN[t] = __builtin_amdgcn_mfma_f32_16x16x32_bf16(a1, bn1, accN[t], 0, 0, 0);
    }

#pragma unroll
    for (int t = 0; t < 4; t++) {
#pragma unroll
        for (int i = 0; i < 4; i++) {
            int n = rbase + kg * 4 + i;       // D row
            if (n < N_NODES) {
                int c = t * 16 + rrow;        // D col
                outR[(size_t)n * D + c] = accR[t][i];
                outN[(size_t)n * D + c] = f2bf(accN[t][i]);
            }
        }
    }
}

// ---------- merged scatter + layer-1 GEMM (block-specialized) ---------------
__global__ void __launch_bounds__(256) scatter_gemm1(
    const int* __restrict__ src, const int* __restrict__ dst,
    int* __restrict__ cursorPad, int* __restrict__ staged,
    const float* __restrict__ X, const unsigned short* __restrict__ wt,
    float* __restrict__ xr, unsigned short* __restrict__ xn) {
    __shared__ char smem[25600];              // scatter role only
    if (blockIdx.x < SBLOCKS) {
        scatter_body(src, dst, cursorPad, staged, smem, blockIdx.x, threadIdx.x);
    } else {
        gemm_mfma_body<0>(X, (const unsigned short*)0,
                          wt + 0 * D * D, wt + 1 * D * D,
                          xr, xn, (blockIdx.x - SBLOCKS) * 64, threadIdx.x);
    }
}

// ---------- standalone layer-2 GEMM (bf16 input, MFMA) ----------------------
__global__ void __launch_bounds__(256) gemm2(
    const unsigned short* __restrict__ Xb, const unsigned short* __restrict__ wt,
    float* __restrict__ hr, unsigned short* __restrict__ hn) {
    gemm_mfma_body<1>((const float*)0, Xb,
                      wt + 2 * D * D, wt + 3 * D * D,
                      hr, hn, blockIdx.x * 64, threadIdx.x);
}

// ---------- per-bucket CSR build (verified R6 fine-bucket form) -------------
__global__ void __launch_bounds__(256) csr_build_kernel(
    const int* __restrict__ cursorPad, const int* __restrict__ staged,
    int* __restrict__ csr, int* __restrict__ startA, int* __restrict__ endA) {
    __shared__ int deg[NPB];
    __shared__ int sc[NPB];
    __shared__ int curs[NPB];
    __shared__ int lcsr[BCAP];
    int k = blockIdx.x;
    int t = threadIdx.x;
    int base = k * BCAP;
    int cnt  = cursorPad[k * 16];
    if (t < NPB) deg[t] = 0;
    __syncthreads();
    for (int i = t; i < cnt; i += 256)
        atomicAdd(&deg[staged[base + i] & 63], 1);
    __syncthreads();
    int v = (t < NPB) ? deg[t] : 0;
    if (t < NPB) sc[t] = v;
    __syncthreads();
#pragma unroll
    for (int d = 1; d < NPB; d <<= 1) {
        int u = (t < NPB && t >= d) ? sc[t - d] : 0;
        __syncthreads();
        if (t < NPB) sc[t] += u;
        __syncthreads();
    }
    if (t < NPB) {
        int start = sc[t] - v;
        int node = k * NPB + t;
        if (node < N_NODES) {
            startA[node] = base + start;
            endA[node]   = base + start + v;
        }
        curs[t] = start;
    }
    __syncthreads();
    for (int i = t; i < cnt; i += 256) {
        int e = staged[base + i];
        int pos = atomicAdd(&curs[e & 63], 1);
        lcsr[pos] = e >> 6;
    }
    __syncthreads();
    for (int i = t; i < cnt; i += 256)
        csr[base + i] = lcsr[i];
}

// ---------- Gather (verified uint4 form) + fused epilogue -------------------
template<int RELU, int OUTBF>
__global__ void __launch_bounds__(256) gather_fused(
    const unsigned short* __restrict__ Gsrc, const float* __restrict__ Root,
    const float* __restrict__ bias,
    const int* __restrict__ startA, const int* __restrict__ endA,
    const int* __restrict__ csr,
    float* __restrict__ outF, unsigned short* __restrict__ outB) {
    int tid = threadIdx.x;
    int wave = tid >> 6, lane = tid & 63;
    int node = blockIdx.x * 4 + wave;
    int sub = lane >> 3, fq = lane & 7;
    int j0 = startA[node], je = endA[node];
    float a0=0.f,a1=0.f,a2=0.f,a3=0.f,a4=0.f,a5=0.f,a6=0.f,a7=0.f;
    for (int jb = j0; jb < je; jb += 64) {          // je wave-uniform
        int idx = jb + lane;
        int p = csr[idx < je ? idx : (je - 1)];     // coalesced index batch
        int m = min(64, je - jb);                   // wave-uniform
        int b = 0;
        for (; b + 16 <= m; b += 16) {
            int i0 = __shfl(p, b + sub, 64);
            int i1 = __shfl(p, b + 8 + sub, 64);
            uint4 u0 = *(const uint4*)(Gsrc + i0 * D + fq * 8);
            uint4 u1 = *(const uint4*)(Gsrc + i1 * D + fq * 8);
            a0 += bflo(u0.x) + bflo(u1.x);  a1 += bfhi(u0.x) + bfhi(u1.x);
            a2 += bflo(u0.y) + bflo(u1.y);  a3 += bfhi(u0.y) + bfhi(u1.y);
            a4 += bflo(u0.z) + bflo(u1.z);  a5 += bfhi(u0.z) + bfhi(u1.z);
            a6 += bflo(u0.w) + bflo(u1.w);  a7 += bfhi(u0.w) + bfhi(u1.w);
        }
        for (; b < m; b += 8) {                     // uniform condition
            int sidx = b + sub;
            int scl = sidx < m ? sidx : (m - 1);    // active source lane
            int i0 = __shfl(p, scl, 64);            // executed by ALL lanes
            if (sidx < m) {                         // divergence only here
                uint4 u = *(const uint4*)(Gsrc + i0 * D + fq * 8);
                a0 += bflo(u.x); a1 += bfhi(u.x);
                a2 += bflo(u.y); a3 += bfhi(u.y);
                a4 += bflo(u.z); a5 += bfhi(u.z);
                a6 += bflo(u.w); a7 += bfhi(u.w);
            }
        }
    }
#pragma unroll
    for (int mk = 8; mk <= 32; mk <<= 1) {
        a0 += __shfl_xor(a0, mk, 64); a1 += __shfl_xor(a1, mk, 64);
        a2 += __shfl_xor(a2, mk, 64); a3 += __shfl_xor(a3, mk, 64);
        a4 += __shfl_xor(a4, mk, 64); a5 += __shfl_xor(a5, mk, 64);
        a6 += __shfl_xor(a6, mk, 64); a7 += __shfl_xor(a7, mk, 64);
    }
    if (sub == 0) {
        const float* rp = Root + (size_t)node * D + fq * 8;
        float4 x0 = *(const float4*)rp;
        float4 x1 = *(const float4*)(rp + 4);
        float4 b0 = ((const float4*)bias)[fq * 2];
        float4 b1 = ((const float4*)bias)[fq * 2 + 1];
        float r0 = a0 + x0.x + b0.x, r1 = a1 + x0.y + b0.y;
        float r2 = a2 + x0.z + b0.z, r3 = a3 + x0.w + b0.w;
        float r4 = a4 + x1.x + b1.x, r5 = a5 + x1.y + b1.y;
        float r6 = a6 + x1.z + b1.z, r7 = a7 + x1.w + b1.w;
        if (RELU) {
            r0 = fmaxf(r0, 0.f); r1 = fmaxf(r1, 0.f);
            r2 = fmaxf(r2, 0.f); r3 = fmaxf(r3, 0.f);
            r4 = fmaxf(r4, 0.f); r5 = fmaxf(r5, 0.f);
            r6 = fmaxf(r6, 0.f); r7 = fmaxf(r7, 0.f);
        }
        if (OUTBF) {
            uint4 u;
            u.x = (unsigned)f2bf(r0) | ((unsigned)f2bf(r1) << 16);
            u.y = (unsigned)f2bf(r2) | ((unsigned)f2bf(r3) << 16);
            u.z = (unsigned)f2bf(r4) | ((unsigned)f2bf(r5) << 16);
            u.w = (unsigned)f2bf(r6) | ((unsigned)f2bf(r7) << 16);
            *(uint4*)(outB + (size_t)node * D + fq * 8) = u;
        } else {
            float4 w0; w0.x = r0; w0.y = r1; w0.z = r2; w0.w = r3;
            float4 w1; w1.x = r4; w1.y = r5; w1.z = r6; w1.w = r7;
            *(float4*)(outF + (size_t)node * D + fq * 8) = w0;
            *(float4*)(outF + (size_t)node * D + fq * 8 + 4) = w1;
        }
    }
}

// ---------- launch ----------------------------------------------------------
extern "C" void kernel_launch(void* const* d_in, const int* in_sizes, int n_in,
                              void* d_out, int out_size, void* d_ws, size_t ws_size,
                              hipStream_t stream) {
    const float* x   = (const float*)d_in[0];
    const int*   edg = (const int*)d_in[1];
    const float* W1r = (const float*)d_in[2];
    const float* W1n = (const float*)d_in[3];
    const float* b1  = (const float*)d_in[4];
    const float* W2r = (const float*)d_in[5];
    const float* W2n = (const float*)d_in[6];
    const float* b2  = (const float*)d_in[7];
    float* out = (float*)d_out;

    const int* src = edg;
    const int* dst = edg + N_EDGES;

    // ws (256 MiB) — non-overlapping layout.
    int* W              = (int*)d_ws;
    int* cursorPad      = W;                          // NBUCKETS*16 ints
    int* staged         = W + NBUCKETS * 16;          // NBUCKETS*BCAP ints
    int* csr            = staged + NBUCKETS * BCAP;   // NBUCKETS*BCAP ints
    int* startA         = csr + NBUCKETS * BCAP;
    int* endA           = startA + N_NODES;
    float* xr           = (float*)(endA + N_NODES);   // fp32 [N][64] root L1
    unsigned short* xn  = (unsigned short*)(xr + (size_t)N_NODES * D); // bf16 x@W1n
    unsigned short* hbf = xn + (size_t)N_NODES * D;   // bf16 h
    float* hr           = (float*)(hbf + (size_t)N_NODES * D);         // fp32 h@W2r
    unsigned short* hn  = (unsigned short*)(hr + (size_t)N_NODES * D); // bf16 h@W2n
    unsigned short* wt  = hn + (size_t)N_NODES * D;   // 4x[64][64] bf16 W^T

    // prep: zero cursors + bf16 W^T (replaces memset dispatch)
    prep_kernel<<<5, 256, 0, stream>>>(W1r, W1n, W2r, W2n, cursorPad, wt);

    // [scatter || layer-1 dual MFMA GEMM]  (xr = x@W1r fp32, xn = x@W1n bf16)
    scatter_gemm1<<<SBLOCKS + MB, 256, 0, stream>>>(
        src, dst, cursorPad, staged, x, wt, xr, xn);

    csr_build_kernel<<<NBUCKETS, 256, 0, stream>>>(cursorPad, staged, csr,
                                                   startA, endA);

    const int GB = N_NODES / 4;          // 12500

    // h = relu(xr + segsum(xn[src]) + b1), written bf16.
    gather_fused<1, 1><<<GB, 256, 0, stream>>>(
        xn, xr, b1, startA, endA, csr, (float*)0, hbf);

    // layer-2 dual MFMA GEMM: hr = h@W2r fp32, hn = h@W2n bf16.
    gemm2<<<MB, 256, 0, stream>>>(hbf, wt, hr, hn);

    // out = hr + segsum(hn[src]) + b2, written fp32.
    gather_fused<0, 0><<<GB, 256, 0, stream>>>(
        hn, hr, b2, startA, endA, csr, out, (unsigned short*)0);
}

// Round 8
// 172.287 us; speedup vs baseline: 1.8533x; 1.0063x over previous
//
#include <hip/hip_runtime.h>

#define N_NODES 50000
#define N_EDGES 800000
#define D 64
#define NBUCKETS 782          // dst>>6, 0..781
#define NPB 64                // nodes per bucket
#define BCAP 2048             // per-bucket capacity (Poisson(1024), huge margin)
#define SBLOCKS 256           // scatter blocks
#define CHUNK (N_EDGES / SBLOCKS)   // 3125
#define MB ((N_NODES + 63) / 64)    // 782 gemm tiles

typedef short bf16x8 __attribute__((ext_vector_type(8)));   // 8 bf16 = 4 VGPRs
typedef float f32x4  __attribute__((ext_vector_type(4)));   // MFMA accumulator

// bf16 helpers (RNE), bit-level.
__device__ __forceinline__ unsigned short f2bf(float f) {
    unsigned u = __float_as_uint(f);
    return (unsigned short)((u + 0x7fffu + ((u >> 16) & 1u)) >> 16);
}
__device__ __forceinline__ float bflo(unsigned u) {
    return __uint_as_float(u << 16);
}
__device__ __forceinline__ float bfhi(unsigned u) {
    return __uint_as_float(u & 0xffff0000u);
}

// ---------- prep: zero cursors + build bf16 W^T for all 4 weights -----------
__global__ void __launch_bounds__(256) prep_kernel(
    const float* __restrict__ W1r, const float* __restrict__ W1n,
    const float* __restrict__ W2r, const float* __restrict__ W2n,
    int* __restrict__ cursorPad, unsigned short* __restrict__ wt) {
    int t = threadIdx.x;
    if (blockIdx.x == 4) {
        for (int i = t; i < NBUCKETS * 16; i += 256) cursorPad[i] = 0;
        return;
    }
    const float* Wsrc = blockIdx.x == 0 ? W1r : blockIdx.x == 1 ? W1n
                      : blockIdx.x == 2 ? W2r : W2n;
    unsigned short* dstw = wt + blockIdx.x * D * D;
    for (int i = t; i < D * D; i += 256) {
        int k = i >> 6, c = i & 63;           // coalesced read of W[k][c]
        dstw[c * D + k] = f2bf(Wsrc[i]);      // transposed bf16 store
    }
}

// ---------- scatter body (verified R3 two-pass form; fine buckets) ----------
__device__ __forceinline__ void scatter_body(
    const int* __restrict__ src, const int* __restrict__ dst,
    int* __restrict__ cursorPad, int* __restrict__ staged,
    char* smem, int bid, int t) {
    int* hist = (int*)smem;
    int* curs = (int*)(smem + 3200);
    int* pk   = (int*)(smem + 6400);
    unsigned short* bk = (unsigned short*)(smem + 6400 + 12500);
    for (int i = t; i < NBUCKETS; i += 256) hist[i] = 0;
    __syncthreads();
    int lo = bid * CHUNK;
    for (int i = t; i < CHUNK; i += 256) {
        int d = dst[lo + i];
        int s = src[lo + i];
        pk[i] = (s << 6) | (d & 63);
        bk[i] = (unsigned short)(d >> 6);
        atomicAdd(&hist[d >> 6], 1);
    }
    __syncthreads();
    for (int k = t; k < NBUCKETS; k += 256)
        if (hist[k] > 0)
            curs[k] = k * BCAP + atomicAdd(&cursorPad[k * 16], hist[k]);
    __syncthreads();
    for (int i = t; i < CHUNK; i += 256) {
        int b = bk[i];
        int pos = atomicAdd(&curs[b], 1);
        staged[pos] = pk[i];
    }
}

// ---------- MFMA dual GEMM body (verified R7 form) --------------------------
template<int XBF>
__device__ __forceinline__ void gemm_mfma_body(
    const float* __restrict__ Xf, const unsigned short* __restrict__ Xb,
    const unsigned short* __restrict__ Wtr, const unsigned short* __restrict__ Wtn,
    float* __restrict__ outR, unsigned short* __restrict__ outN,
    int node0, int tid) {
    int wave = tid >> 6, lane = tid & 63;
    int rbase = node0 + wave * 16;            // 16 nodes per wave
    int rrow  = lane & 15;
    int kg    = lane >> 4;                    // k-chunk selector (0..3)
    int row   = min(rbase + rrow, N_NODES - 1);

    bf16x8 a0, a1;                            // k 0..31 / 32..63
    if (XBF) {
        a0 = *(const bf16x8*)(Xb + (size_t)row * D + kg * 8);
        a1 = *(const bf16x8*)(Xb + (size_t)row * D + 32 + kg * 8);
    } else {
        const float* xp = Xf + (size_t)row * D + kg * 8;
#pragma unroll
        for (int j = 0; j < 8; j++) a0[j] = (short)f2bf(xp[j]);
#pragma unroll
        for (int j = 0; j < 8; j++) a1[j] = (short)f2bf(xp[32 + j]);
    }

    f32x4 accR[4], accN[4];
#pragma unroll
    for (int t = 0; t < 4; t++) {
        accR[t][0] = 0.f; accR[t][1] = 0.f; accR[t][2] = 0.f; accR[t][3] = 0.f;
        accN[t][0] = 0.f; accN[t][1] = 0.f; accN[t][2] = 0.f; accN[t][3] = 0.f;
    }

#pragma unroll
    for (int t = 0; t < 4; t++) {
        int c = t * 16 + rrow;                // W^T row = W column
        bf16x8 br0 = *(const bf16x8*)(Wtr + c * D + kg * 8);
        bf16x8 br1 = *(const bf16x8*)(Wtr + c * D + 32 + kg * 8);
        bf16x8 bn0 = *(const bf16x8*)(Wtn + c * D + kg * 8);
        bf16x8 bn1 = *(const bf16x8*)(Wtn + c * D + 32 + kg * 8);
        accR[t] = __builtin_amdgcn_mfma_f32_16x16x32_bf16(a0, br0, accR[t], 0, 0, 0);
        accR[t] = __builtin_amdgcn_mfma_f32_16x16x32_bf16(a1, br1, accR[t], 0, 0, 0);
        accN[t] = __builtin_amdgcn_mfma_f32_16x16x32_bf16(a0, bn0, accN[t], 0, 0, 0);
        accN[t] = __builtin_amdgcn_mfma_f32_16x16x32_bf16(a1, bn1, accN[t], 0, 0, 0);
    }

#pragma unroll
    for (int t = 0; t < 4; t++) {
#pragma unroll
        for (int i = 0; i < 4; i++) {
            int n = rbase + kg * 4 + i;       // D row
            if (n < N_NODES) {
                int c = t * 16 + rrow;        // D col
                outR[(size_t)n * D + c] = accR[t][i];
                outN[(size_t)n * D + c] = f2bf(accN[t][i]);
            }
        }
    }
}

// ---------- merged scatter + layer-1 GEMM (block-specialized) ---------------
__global__ void __launch_bounds__(256) scatter_gemm1(
    const int* __restrict__ src, const int* __restrict__ dst,
    int* __restrict__ cursorPad, int* __restrict__ staged,
    const float* __restrict__ X, const unsigned short* __restrict__ wt,
    float* __restrict__ xr, unsigned short* __restrict__ xn) {
    __shared__ char smem[25600];              // scatter role only
    if (blockIdx.x < SBLOCKS) {
        scatter_body(src, dst, cursorPad, staged, smem, blockIdx.x, threadIdx.x);
    } else {
        gemm_mfma_body<0>(X, (const unsigned short*)0,
                          wt + 0 * D * D, wt + 1 * D * D,
                          xr, xn, (blockIdx.x - SBLOCKS) * 64, threadIdx.x);
    }
}

// ---------- standalone layer-2 GEMM (bf16 input, MFMA) ----------------------
__global__ void __launch_bounds__(256) gemm2(
    const unsigned short* __restrict__ Xb, const unsigned short* __restrict__ wt,
    float* __restrict__ hr, unsigned short* __restrict__ hn) {
    gemm_mfma_body<1>((const float*)0, Xb,
                      wt + 2 * D * D, wt + 3 * D * D,
                      hr, hn, blockIdx.x * 64, threadIdx.x);
}

// ---------- per-bucket CSR build (R6 form; packed startEnd int2) ------------
__global__ void __launch_bounds__(256) csr_build_kernel(
    const int* __restrict__ cursorPad, const int* __restrict__ staged,
    int* __restrict__ csr, int* __restrict__ startEnd) {
    __shared__ int deg[NPB];
    __shared__ int sc[NPB];
    __shared__ int curs[NPB];
    __shared__ int lcsr[BCAP];
    int k = blockIdx.x;
    int t = threadIdx.x;
    int base = k * BCAP;
    int cnt  = cursorPad[k * 16];
    if (t < NPB) deg[t] = 0;
    __syncthreads();
    for (int i = t; i < cnt; i += 256)
        atomicAdd(&deg[staged[base + i] & 63], 1);
    __syncthreads();
    int v = (t < NPB) ? deg[t] : 0;
    if (t < NPB) sc[t] = v;
    __syncthreads();
#pragma unroll
    for (int d = 1; d < NPB; d <<= 1) {
        int u = (t < NPB && t >= d) ? sc[t - d] : 0;
        __syncthreads();
        if (t < NPB) sc[t] += u;
        __syncthreads();
    }
    if (t < NPB) {
        int start = sc[t] - v;
        int node = k * NPB + t;
        if (node < N_NODES) {
            int2 se; se.x = base + start; se.y = base + start + v;
            ((int2*)startEnd)[node] = se;          // packed {start,end}
        }
        curs[t] = start;
    }
    __syncthreads();
    for (int i = t; i < cnt; i += 256) {
        int e = staged[base + i];
        int pos = atomicAdd(&curs[e & 63], 1);
        lcsr[pos] = e >> 6;
    }
    __syncthreads();
    for (int i = t; i < cnt; i += 256)
        csr[base + i] = lcsr[i];
}

// ---------- Gather: 2 nodes/wave, interleaved chains + fused epilogue -------
// Per-node batch body is the verified uint4 form, bit-identical order.
template<int RELU, int OUTBF>
__global__ void __launch_bounds__(256) gather_fused(
    const unsigned short* __restrict__ Gsrc, const float* __restrict__ Root,
    const float* __restrict__ bias,
    const int* __restrict__ startEnd, const int* __restrict__ csr,
    float* __restrict__ outF, unsigned short* __restrict__ outB) {
    int tid = threadIdx.x;
    int wave = tid >> 6, lane = tid & 63;
    int nA = blockIdx.x * 8 + wave * 2;       // even; nB = nA+1 (< N_NODES)
    int nB = nA + 1;
    int sub = lane >> 3, fq = lane & 7;

    // one dwordx4: ranges for BOTH nodes (adjacent int2s)
    int4 se = *(const int4*)(startEnd + nA * 2);
    int jbA = se.x, jeA = se.y, jbB = se.z, jeB = se.w;

    // hoist epilogue loads (independent of gather; sub==0 lanes only)
    float4 xA0, xA1, xB0, xB1, b0, b1;
    if (sub == 0) {
        const float* rpA = Root + (size_t)nA * D + fq * 8;
        const float* rpB = Root + (size_t)nB * D + fq * 8;
        xA0 = *(const float4*)rpA; xA1 = *(const float4*)(rpA + 4);
        xB0 = *(const float4*)rpB; xB1 = *(const float4*)(rpB + 4);
        b0 = ((const float4*)bias)[fq * 2];
        b1 = ((const float4*)bias)[fq * 2 + 1];
    }

    float aA0=0.f,aA1=0.f,aA2=0.f,aA3=0.f,aA4=0.f,aA5=0.f,aA6=0.f,aA7=0.f;
    float aB0=0.f,aB1=0.f,aB2=0.f,aB3=0.f,aB4=0.f,aB5=0.f,aB6=0.f,aB7=0.f;

    while (jbA < jeA || jbB < jeB) {          // wave-uniform
        int pA = 0, pB = 0, mA = 0, mB = 0;
        if (jbA < jeA) {                      // wave-uniform
            int idx = jbA + lane;
            pA = csr[idx < jeA ? idx : (jeA - 1)];
            mA = min(64, jeA - jbA);
        }
        if (jbB < jeB) {
            int idx = jbB + lane;
            pB = csr[idx < jeB ? idx : (jeB - 1)];
            mB = min(64, jeB - jbB);
        }
        if (mA) {
            int b = 0;
            for (; b + 16 <= mA; b += 16) {
                int i0 = __shfl(pA, b + sub, 64);
                int i1 = __shfl(pA, b + 8 + sub, 64);
                uint4 u0 = *(const uint4*)(Gsrc + i0 * D + fq * 8);
                uint4 u1 = *(const uint4*)(Gsrc + i1 * D + fq * 8);
                aA0 += bflo(u0.x) + bflo(u1.x);  aA1 += bfhi(u0.x) + bfhi(u1.x);
                aA2 += bflo(u0.y) + bflo(u1.y);  aA3 += bfhi(u0.y) + bfhi(u1.y);
                aA4 += bflo(u0.z) + bflo(u1.z);  aA5 += bfhi(u0.z) + bfhi(u1.z);
                aA6 += bflo(u0.w) + bflo(u1.w);  aA7 += bfhi(u0.w) + bfhi(u1.w);
            }
            for (; b < mA; b += 8) {
                int sidx = b + sub;
                int scl = sidx < mA ? sidx : (mA - 1);
                int i0 = __shfl(pA, scl, 64);
                if (sidx < mA) {
                    uint4 u = *(const uint4*)(Gsrc + i0 * D + fq * 8);
                    aA0 += bflo(u.x); aA1 += bfhi(u.x);
                    aA2 += bflo(u.y); aA3 += bfhi(u.y);
                    aA4 += bflo(u.z); aA5 += bfhi(u.z);
                    aA6 += bflo(u.w); aA7 += bfhi(u.w);
                }
            }
        }
        if (mB) {
            int b = 0;
            for (; b + 16 <= mB; b += 16) {
                int i0 = __shfl(pB, b + sub, 64);
                int i1 = __shfl(pB, b + 8 + sub, 64);
                uint4 u0 = *(const uint4*)(Gsrc + i0 * D + fq * 8);
                uint4 u1 = *(const uint4*)(Gsrc + i1 * D + fq * 8);
                aB0 += bflo(u0.x) + bflo(u1.x);  aB1 += bfhi(u0.x) + bfhi(u1.x);
                aB2 += bflo(u0.y) + bflo(u1.y);  aB3 += bfhi(u0.y) + bfhi(u1.y);
                aB4 += bflo(u0.z) + bflo(u1.z);  aB5 += bfhi(u0.z) + bfhi(u1.z);
                aB6 += bflo(u0.w) + bflo(u1.w);  aB7 += bfhi(u0.w) + bfhi(u1.w);
            }
            for (; b < mB; b += 8) {
                int sidx = b + sub;
                int scl = sidx < mB ? sidx : (mB - 1);
                int i0 = __shfl(pB, scl, 64);
                if (sidx < mB) {
                    uint4 u = *(const uint4*)(Gsrc + i0 * D + fq * 8);
                    aB0 += bflo(u.x); aB1 += bfhi(u.x);
                    aB2 += bflo(u.y); aB3 += bfhi(u.y);
                    aB4 += bflo(u.z); aB5 += bfhi(u.z);
                    aB6 += bflo(u.w); aB7 += bfhi(u.w);
                }
            }
        }
        jbA += 64; jbB += 64;
    }

#pragma unroll
    for (int mk = 8; mk <= 32; mk <<= 1) {
        aA0 += __shfl_xor(aA0, mk, 64); aA1 += __shfl_xor(aA1, mk, 64);
        aA2 += __shfl_xor(aA2, mk, 64); aA3 += __shfl_xor(aA3, mk, 64);
        aA4 += __shfl_xor(aA4, mk, 64); aA5 += __shfl_xor(aA5, mk, 64);
        aA6 += __shfl_xor(aA6, mk, 64); aA7 += __shfl_xor(aA7, mk, 64);
        aB0 += __shfl_xor(aB0, mk, 64); aB1 += __shfl_xor(aB1, mk, 64);
        aB2 += __shfl_xor(aB2, mk, 64); aB3 += __shfl_xor(aB3, mk, 64);
        aB4 += __shfl_xor(aB4, mk, 64); aB5 += __shfl_xor(aB5, mk, 64);
        aB6 += __shfl_xor(aB6, mk, 64); aB7 += __shfl_xor(aB7, mk, 64);
    }
    if (sub == 0) {
        float r0 = aA0 + xA0.x + b0.x, r1 = aA1 + xA0.y + b0.y;
        float r2 = aA2 + xA0.z + b0.z, r3 = aA3 + xA0.w + b0.w;
        float r4 = aA4 + xA1.x + b1.x, r5 = aA5 + xA1.y + b1.y;
        float r6 = aA6 + xA1.z + b1.z, r7 = aA7 + xA1.w + b1.w;
        float s0 = aB0 + xB0.x + b0.x, s1 = aB1 + xB0.y + b0.y;
        float s2 = aB2 + xB0.z + b0.z, s3 = aB3 + xB0.w + b0.w;
        float s4 = aB4 + xB1.x + b1.x, s5 = aB5 + xB1.y + b1.y;
        float s6 = aB6 + xB1.z + b1.z, s7 = aB7 + xB1.w + b1.w;
        if (RELU) {
            r0 = fmaxf(r0, 0.f); r1 = fmaxf(r1, 0.f);
            r2 = fmaxf(r2, 0.f); r3 = fmaxf(r3, 0.f);
            r4 = fmaxf(r4, 0.f); r5 = fmaxf(r5, 0.f);
            r6 = fmaxf(r6, 0.f); r7 = fmaxf(r7, 0.f);
            s0 = fmaxf(s0, 0.f); s1 = fmaxf(s1, 0.f);
            s2 = fmaxf(s2, 0.f); s3 = fmaxf(s3, 0.f);
            s4 = fmaxf(s4, 0.f); s5 = fmaxf(s5, 0.f);
            s6 = fmaxf(s6, 0.f); s7 = fmaxf(s7, 0.f);
        }
        if (OUTBF) {
            uint4 u;
            u.x = (unsigned)f2bf(r0) | ((unsigned)f2bf(r1) << 16);
            u.y = (unsigned)f2bf(r2) | ((unsigned)f2bf(r3) << 16);
            u.z = (unsigned)f2bf(r4) | ((unsigned)f2bf(r5) << 16);
            u.w = (unsigned)f2bf(r6) | ((unsigned)f2bf(r7) << 16);
            *(uint4*)(outB + (size_t)nA * D + fq * 8) = u;
            u.x = (unsigned)f2bf(s0) | ((unsigned)f2bf(s1) << 16);
            u.y = (unsigned)f2bf(s2) | ((unsigned)f2bf(s3) << 16);
            u.z = (unsigned)f2bf(s4) | ((unsigned)f2bf(s5) << 16);
            u.w = (unsigned)f2bf(s6) | ((unsigned)f2bf(s7) << 16);
            *(uint4*)(outB + (size_t)nB * D + fq * 8) = u;
        } else {
            float4 w0; w0.x = r0; w0.y = r1; w0.z = r2; w0.w = r3;
            float4 w1; w1.x = r4; w1.y = r5; w1.z = r6; w1.w = r7;
            *(float4*)(outF + (size_t)nA * D + fq * 8) = w0;
            *(float4*)(outF + (size_t)nA * D + fq * 8 + 4) = w1;
            w0.x = s0; w0.y = s1; w0.z = s2; w0.w = s3;
            w1.x = s4; w1.y = s5; w1.z = s6; w1.w = s7;
            *(float4*)(outF + (size_t)nB * D + fq * 8) = w0;
            *(float4*)(outF + (size_t)nB * D + fq * 8 + 4) = w1;
        }
    }
}

// ---------- launch ----------------------------------------------------------
extern "C" void kernel_launch(void* const* d_in, const int* in_sizes, int n_in,
                              void* d_out, int out_size, void* d_ws, size_t ws_size,
                              hipStream_t stream) {
    const float* x   = (const float*)d_in[0];
    const int*   edg = (const int*)d_in[1];
    const float* W1r = (const float*)d_in[2];
    const float* W1n = (const float*)d_in[3];
    const float* b1  = (const float*)d_in[4];
    const float* W2r = (const float*)d_in[5];
    const float* W2n = (const float*)d_in[6];
    const float* b2  = (const float*)d_in[7];
    float* out = (float*)d_out;

    const int* src = edg;
    const int* dst = edg + N_EDGES;

    // ws (256 MiB) — non-overlapping layout.
    int* W              = (int*)d_ws;
    int* cursorPad      = W;                          // NBUCKETS*16 ints
    int* staged         = W + NBUCKETS * 16;          // NBUCKETS*BCAP ints
    int* csr            = staged + NBUCKETS * BCAP;   // NBUCKETS*BCAP ints
    int* startEnd       = csr + NBUCKETS * BCAP;      // N_NODES int2 (packed)
    float* xr           = (float*)(startEnd + 2 * N_NODES); // fp32 [N][64]
    unsigned short* xn  = (unsigned short*)(xr + (size_t)N_NODES * D); // bf16 x@W1n
    unsigned short* hbf = xn + (size_t)N_NODES * D;   // bf16 h
    float* hr           = (float*)(hbf + (size_t)N_NODES * D);         // fp32 h@W2r
    unsigned short* hn  = (unsigned short*)(hr + (size_t)N_NODES * D); // bf16 h@W2n
    unsigned short* wt  = hn + (size_t)N_NODES * D;   // 4x[64][64] bf16 W^T

    // prep: zero cursors + bf16 W^T
    prep_kernel<<<5, 256, 0, stream>>>(W1r, W1n, W2r, W2n, cursorPad, wt);

    // [scatter || layer-1 dual MFMA GEMM]  (xr = x@W1r fp32, xn = x@W1n bf16)
    scatter_gemm1<<<SBLOCKS + MB, 256, 0, stream>>>(
        src, dst, cursorPad, staged, x, wt, xr, xn);

    csr_build_kernel<<<NBUCKETS, 256, 0, stream>>>(cursorPad, staged, csr,
                                                   startEnd);

    const int GB2 = N_NODES / 8;         // 6250 (2 nodes per wave)

    // h = relu(xr + segsum(xn[src]) + b1), written bf16.
    gather_fused<1, 1><<<GB2, 256, 0, stream>>>(
        xn, xr, b1, startEnd, csr, (float*)0, hbf);

    // layer-2 dual MFMA GEMM: hr = h@W2r fp32, hn = h@W2n bf16.
    gemm2<<<MB, 256, 0, stream>>>(hbf, wt, hr, hn);

    // out = hr + segsum(hn[src]) + b2, written fp32.
    gather_fused<0, 0><<<GB2, 256, 0, stream>>>(
        hn, hr, b2, startEnd, csr, out, (unsigned short*)0);
}

// Round 9
// 168.929 us; speedup vs baseline: 1.8902x; 1.0199x over previous
//
#include <hip/hip_runtime.h>

#define N_NODES 50000
#define N_EDGES 800000
#define D 64
#define NBUCKETS 782          // dst>>6, 0..781
#define NPB 64                // nodes per bucket
#define BCAP 2048             // per-bucket capacity (Poisson(1024), huge margin)
#define SBLOCKS 256           // scatter blocks
#define CHUNK (N_EDGES / SBLOCKS)   // 3125
#define MB ((N_NODES + 63) / 64)    // 782 gemm tiles

typedef short bf16x8 __attribute__((ext_vector_type(8)));   // 8 bf16 = 4 VGPRs
typedef float f32x4  __attribute__((ext_vector_type(4)));   // MFMA accumulator

// bf16 helpers (RNE), bit-level.
__device__ __forceinline__ unsigned short f2bf(float f) {
    unsigned u = __float_as_uint(f);
    return (unsigned short)((u + 0x7fffu + ((u >> 16) & 1u)) >> 16);
}
__device__ __forceinline__ float bflo(unsigned u) {
    return __uint_as_float(u << 16);
}
__device__ __forceinline__ float bfhi(unsigned u) {
    return __uint_as_float(u & 0xffff0000u);
}

// ---------- prep: zero cursors + build bf16 W^T for all 4 weights -----------
__global__ void __launch_bounds__(256) prep_kernel(
    const float* __restrict__ W1r, const float* __restrict__ W1n,
    const float* __restrict__ W2r, const float* __restrict__ W2n,
    int* __restrict__ cursorPad, unsigned short* __restrict__ wt) {
    int t = threadIdx.x;
    if (blockIdx.x == 4) {
        for (int i = t; i < NBUCKETS * 16; i += 256) cursorPad[i] = 0;
        return;
    }
    const float* Wsrc = blockIdx.x == 0 ? W1r : blockIdx.x == 1 ? W1n
                      : blockIdx.x == 2 ? W2r : W2n;
    unsigned short* dstw = wt + blockIdx.x * D * D;
    for (int i = t; i < D * D; i += 256) {
        int k = i >> 6, c = i & 63;           // coalesced read of W[k][c]
        dstw[c * D + k] = f2bf(Wsrc[i]);      // transposed bf16 store
    }
}

// ---------- scatter body (verified R3 two-pass form; fine buckets) ----------
__device__ __forceinline__ void scatter_body(
    const int* __restrict__ src, const int* __restrict__ dst,
    int* __restrict__ cursorPad, int* __restrict__ staged,
    char* smem, int bid, int t) {
    int* hist = (int*)smem;
    int* curs = (int*)(smem + 3200);
    int* pk   = (int*)(smem + 6400);
    unsigned short* bk = (unsigned short*)(smem + 6400 + 12500);
    for (int i = t; i < NBUCKETS; i += 256) hist[i] = 0;
    __syncthreads();
    int lo = bid * CHUNK;
    for (int i = t; i < CHUNK; i += 256) {
        int d = dst[lo + i];
        int s = src[lo + i];
        pk[i] = (s << 6) | (d & 63);
        bk[i] = (unsigned short)(d >> 6);
        atomicAdd(&hist[d >> 6], 1);
    }
    __syncthreads();
    for (int k = t; k < NBUCKETS; k += 256)
        if (hist[k] > 0)
            curs[k] = k * BCAP + atomicAdd(&cursorPad[k * 16], hist[k]);
    __syncthreads();
    for (int i = t; i < CHUNK; i += 256) {
        int b = bk[i];
        int pos = atomicAdd(&curs[b], 1);
        staged[pos] = pk[i];
    }
}

// ---------- MFMA dual GEMM body (verified R7 form) --------------------------
template<int XBF>
__device__ __forceinline__ void gemm_mfma_body(
    const float* __restrict__ Xf, const unsigned short* __restrict__ Xb,
    const unsigned short* __restrict__ Wtr, const unsigned short* __restrict__ Wtn,
    float* __restrict__ outR, unsigned short* __restrict__ outN,
    int node0, int tid) {
    int wave = tid >> 6, lane = tid & 63;
    int rbase = node0 + wave * 16;            // 16 nodes per wave
    int rrow  = lane & 15;
    int kg    = lane >> 4;                    // k-chunk selector (0..3)
    int row   = min(rbase + rrow, N_NODES - 1);

    bf16x8 a0, a1;                            // k 0..31 / 32..63
    if (XBF) {
        a0 = *(const bf16x8*)(Xb + (size_t)row * D + kg * 8);
        a1 = *(const bf16x8*)(Xb + (size_t)row * D + 32 + kg * 8);
    } else {
        const float* xp = Xf + (size_t)row * D + kg * 8;
#pragma unroll
        for (int j = 0; j < 8; j++) a0[j] = (short)f2bf(xp[j]);
#pragma unroll
        for (int j = 0; j < 8; j++) a1[j] = (short)f2bf(xp[32 + j]);
    }

    f32x4 accR[4], accN[4];
#pragma unroll
    for (int t = 0; t < 4; t++) {
        accR[t][0] = 0.f; accR[t][1] = 0.f; accR[t][2] = 0.f; accR[t][3] = 0.f;
        accN[t][0] = 0.f; accN[t][1] = 0.f; accN[t][2] = 0.f; accN[t][3] = 0.f;
    }

#pragma unroll
    for (int t = 0; t < 4; t++) {
        int c = t * 16 + rrow;                // W^T row = W column
        bf16x8 br0 = *(const bf16x8*)(Wtr + c * D + kg * 8);
        bf16x8 br1 = *(const bf16x8*)(Wtr + c * D + 32 + kg * 8);
        bf16x8 bn0 = *(const bf16x8*)(Wtn + c * D + kg * 8);
        bf16x8 bn1 = *(const bf16x8*)(Wtn + c * D + 32 + kg * 8);
        accR[t] = __builtin_amdgcn_mfma_f32_16x16x32_bf16(a0, br0, accR[t], 0, 0, 0);
        accR[t] = __builtin_amdgcn_mfma_f32_16x16x32_bf16(a1, br1, accR[t], 0, 0, 0);
        accN[t] = __builtin_amdgcn_mfma_f32_16x16x32_bf16(a0, bn0, accN[t], 0, 0, 0);
        accN[t] = __builtin_amdgcn_mfma_f32_16x16x32_bf16(a1, bn1, accN[t], 0, 0, 0);
    }

#pragma unroll
    for (int t = 0; t < 4; t++) {
#pragma unroll
        for (int i = 0; i < 4; i++) {
            int n = rbase + kg * 4 + i;       // D row
            if (n < N_NODES) {
                int c = t * 16 + rrow;        // D col
                outR[(size_t)n * D + c] = accR[t][i];
                outN[(size_t)n * D + c] = f2bf(accN[t][i]);
            }
        }
    }
}

// ---------- merged scatter + layer-1 GEMM (block-specialized) ---------------
__global__ void __launch_bounds__(256) scatter_gemm1(
    const int* __restrict__ src, const int* __restrict__ dst,
    int* __restrict__ cursorPad, int* __restrict__ staged,
    const float* __restrict__ X, const unsigned short* __restrict__ wt,
    float* __restrict__ xr, unsigned short* __restrict__ xn) {
    __shared__ char smem[25600];              // scatter role only
    if (blockIdx.x < SBLOCKS) {
        scatter_body(src, dst, cursorPad, staged, smem, blockIdx.x, threadIdx.x);
    } else {
        gemm_mfma_body<0>(X, (const unsigned short*)0,
                          wt + 0 * D * D, wt + 1 * D * D,
                          xr, xn, (blockIdx.x - SBLOCKS) * 64, threadIdx.x);
    }
}

// ---------- per-bucket CSR build (R6 form; packed startEnd int2) ------------
__global__ void __launch_bounds__(256) csr_build_kernel(
    const int* __restrict__ cursorPad, const int* __restrict__ staged,
    int* __restrict__ csr, int* __restrict__ startEnd) {
    __shared__ int deg[NPB];
    __shared__ int sc[NPB];
    __shared__ int curs[NPB];
    __shared__ int lcsr[BCAP];
    int k = blockIdx.x;
    int t = threadIdx.x;
    int base = k * BCAP;
    int cnt  = cursorPad[k * 16];
    if (t < NPB) deg[t] = 0;
    __syncthreads();
    for (int i = t; i < cnt; i += 256)
        atomicAdd(&deg[staged[base + i] & 63], 1);
    __syncthreads();
    int v = (t < NPB) ? deg[t] : 0;
    if (t < NPB) sc[t] = v;
    __syncthreads();
#pragma unroll
    for (int d = 1; d < NPB; d <<= 1) {
        int u = (t < NPB && t >= d) ? sc[t - d] : 0;
        __syncthreads();
        if (t < NPB) sc[t] += u;
        __syncthreads();
    }
    if (t < NPB) {
        int start = sc[t] - v;
        int node = k * NPB + t;
        if (node < N_NODES) {
            int2 se; se.x = base + start; se.y = base + start + v;
            ((int2*)startEnd)[node] = se;          // packed {start,end}
        }
        curs[t] = start;
    }
    __syncthreads();
    for (int i = t; i < cnt; i += 256) {
        int e = staged[base + i];
        int pos = atomicAdd(&curs[e & 63], 1);
        lcsr[pos] = e >> 6;
    }
    __syncthreads();
    for (int i = t; i < cnt; i += 256)
        csr[base + i] = lcsr[i];
}

// ---------- fused layer-1 gather + layer-2 GEMM -----------------------------
// 512 threads = 8 waves x 2 nodes = 16 nodes/block (50000 = 3125 x 16 exact).
// Phase A: R8-verified 2-node gather body; epilogue writes relu'd h (bf16)
// into a padded LDS tile instead of global hbf.
// Phase B: dual MFMA GEMM (R7-verified fragment mapping); wave w handles
// column-tile (w>>1) for output kind (w&1): 0 -> hr fp32, 1 -> hn bf16.
__global__ void __launch_bounds__(512) gather1_gemm2(
    const unsigned short* __restrict__ Gsrc, const float* __restrict__ Root,
    const float* __restrict__ bias,
    const int* __restrict__ startEnd, const int* __restrict__ csr,
    const unsigned short* __restrict__ wt,
    float* __restrict__ hr, unsigned short* __restrict__ hn) {
    __shared__ unsigned short hlds[16][72];   // 16 h rows, pitch 72 (2-way banks)
    int tid = threadIdx.x;
    int wave = tid >> 6, lane = tid & 63;
    int n0 = blockIdx.x * 16;
    int nA = n0 + wave * 2;
    int nB = nA + 1;
    int sub = lane >> 3, fq = lane & 7;

    int4 se = *(const int4*)(startEnd + nA * 2);
    int jbA = se.x, jeA = se.y, jbB = se.z, jeB = se.w;

    float4 xA0, xA1, xB0, xB1, b0, b1;
    if (sub == 0) {
        const float* rpA = Root + (size_t)nA * D + fq * 8;
        const float* rpB = Root + (size_t)nB * D + fq * 8;
        xA0 = *(const float4*)rpA; xA1 = *(const float4*)(rpA + 4);
        xB0 = *(const float4*)rpB; xB1 = *(const float4*)(rpB + 4);
        b0 = ((const float4*)bias)[fq * 2];
        b1 = ((const float4*)bias)[fq * 2 + 1];
    }

    float aA0=0.f,aA1=0.f,aA2=0.f,aA3=0.f,aA4=0.f,aA5=0.f,aA6=0.f,aA7=0.f;
    float aB0=0.f,aB1=0.f,aB2=0.f,aB3=0.f,aB4=0.f,aB5=0.f,aB6=0.f,aB7=0.f;

    while (jbA < jeA || jbB < jeB) {          // wave-uniform
        int pA = 0, pB = 0, mA = 0, mB = 0;
        if (jbA < jeA) {
            int idx = jbA + lane;
            pA = csr[idx < jeA ? idx : (jeA - 1)];
            mA = min(64, jeA - jbA);
        }
        if (jbB < jeB) {
            int idx = jbB + lane;
            pB = csr[idx < jeB ? idx : (jeB - 1)];
            mB = min(64, jeB - jbB);
        }
        if (mA) {
            int b = 0;
            for (; b + 16 <= mA; b += 16) {
                int i0 = __shfl(pA, b + sub, 64);
                int i1 = __shfl(pA, b + 8 + sub, 64);
                uint4 u0 = *(const uint4*)(Gsrc + i0 * D + fq * 8);
                uint4 u1 = *(const uint4*)(Gsrc + i1 * D + fq * 8);
                aA0 += bflo(u0.x) + bflo(u1.x);  aA1 += bfhi(u0.x) + bfhi(u1.x);
                aA2 += bflo(u0.y) + bflo(u1.y);  aA3 += bfhi(u0.y) + bfhi(u1.y);
                aA4 += bflo(u0.z) + bflo(u1.z);  aA5 += bfhi(u0.z) + bfhi(u1.z);
                aA6 += bflo(u0.w) + bflo(u1.w);  aA7 += bfhi(u0.w) + bfhi(u1.w);
            }
            for (; b < mA; b += 8) {
                int sidx = b + sub;
                int scl = sidx < mA ? sidx : (mA - 1);
                int i0 = __shfl(pA, scl, 64);
                if (sidx < mA) {
                    uint4 u = *(const uint4*)(Gsrc + i0 * D + fq * 8);
                    aA0 += bflo(u.x); aA1 += bfhi(u.x);
                    aA2 += bflo(u.y); aA3 += bfhi(u.y);
                    aA4 += bflo(u.z); aA5 += bfhi(u.z);
                    aA6 += bflo(u.w); aA7 += bfhi(u.w);
                }
            }
        }
        if (mB) {
            int b = 0;
            for (; b + 16 <= mB; b += 16) {
                int i0 = __shfl(pB, b + sub, 64);
                int i1 = __shfl(pB, b + 8 + sub, 64);
                uint4 u0 = *(const uint4*)(Gsrc + i0 * D + fq * 8);
                uint4 u1 = *(const uint4*)(Gsrc + i1 * D + fq * 8);
                aB0 += bflo(u0.x) + bflo(u1.x);  aB1 += bfhi(u0.x) + bfhi(u1.x);
                aB2 += bflo(u0.y) + bflo(u1.y);  aB3 += bfhi(u0.y) + bfhi(u1.y);
                aB4 += bflo(u0.z) + bflo(u1.z);  aB5 += bfhi(u0.z) + bfhi(u1.z);
                aB6 += bflo(u0.w) + bflo(u1.w);  aB7 += bfhi(u0.w) + bfhi(u1.w);
            }
            for (; b < mB; b += 8) {
                int sidx = b + sub;
                int scl = sidx < mB ? sidx : (mB - 1);
                int i0 = __shfl(pB, scl, 64);
                if (sidx < mB) {
                    uint4 u = *(const uint4*)(Gsrc + i0 * D + fq * 8);
                    aB0 += bflo(u.x); aB1 += bfhi(u.x);
                    aB2 += bflo(u.y); aB3 += bfhi(u.y);
                    aB4 += bflo(u.z); aB5 += bfhi(u.z);
                    aB6 += bflo(u.w); aB7 += bfhi(u.w);
                }
            }
        }
        jbA += 64; jbB += 64;
    }

#pragma unroll
    for (int mk = 8; mk <= 32; mk <<= 1) {
        aA0 += __shfl_xor(aA0, mk, 64); aA1 += __shfl_xor(aA1, mk, 64);
        aA2 += __shfl_xor(aA2, mk, 64); aA3 += __shfl_xor(aA3, mk, 64);
        aA4 += __shfl_xor(aA4, mk, 64); aA5 += __shfl_xor(aA5, mk, 64);
        aA6 += __shfl_xor(aA6, mk, 64); aA7 += __shfl_xor(aA7, mk, 64);
        aB0 += __shfl_xor(aB0, mk, 64); aB1 += __shfl_xor(aB1, mk, 64);
        aB2 += __shfl_xor(aB2, mk, 64); aB3 += __shfl_xor(aB3, mk, 64);
        aB4 += __shfl_xor(aB4, mk, 64); aB5 += __shfl_xor(aB5, mk, 64);
        aB6 += __shfl_xor(aB6, mk, 64); aB7 += __shfl_xor(aB7, mk, 64);
    }
    if (sub == 0) {
        float r0 = fmaxf(aA0 + xA0.x + b0.x, 0.f), r1 = fmaxf(aA1 + xA0.y + b0.y, 0.f);
        float r2 = fmaxf(aA2 + xA0.z + b0.z, 0.f), r3 = fmaxf(aA3 + xA0.w + b0.w, 0.f);
        float r4 = fmaxf(aA4 + xA1.x + b1.x, 0.f), r5 = fmaxf(aA5 + xA1.y + b1.y, 0.f);
        float r6 = fmaxf(aA6 + xA1.z + b1.z, 0.f), r7 = fmaxf(aA7 + xA1.w + b1.w, 0.f);
        float s0 = fmaxf(aB0 + xB0.x + b0.x, 0.f), s1 = fmaxf(aB1 + xB0.y + b0.y, 0.f);
        float s2 = fmaxf(aB2 + xB0.z + b0.z, 0.f), s3 = fmaxf(aB3 + xB0.w + b0.w, 0.f);
        float s4 = fmaxf(aB4 + xB1.x + b1.x, 0.f), s5 = fmaxf(aB5 + xB1.y + b1.y, 0.f);
        float s6 = fmaxf(aB6 + xB1.z + b1.z, 0.f), s7 = fmaxf(aB7 + xB1.w + b1.w, 0.f);
        uint4 u;
        u.x = (unsigned)f2bf(r0) | ((unsigned)f2bf(r1) << 16);
        u.y = (unsigned)f2bf(r2) | ((unsigned)f2bf(r3) << 16);
        u.z = (unsigned)f2bf(r4) | ((unsigned)f2bf(r5) << 16);
        u.w = (unsigned)f2bf(r6) | ((unsigned)f2bf(r7) << 16);
        *(uint4*)&hlds[wave * 2][fq * 8] = u;       // pitch 144B, 16B aligned
        u.x = (unsigned)f2bf(s0) | ((unsigned)f2bf(s1) << 16);
        u.y = (unsigned)f2bf(s2) | ((unsigned)f2bf(s3) << 16);
        u.z = (unsigned)f2bf(s4) | ((unsigned)f2bf(s5) << 16);
        u.w = (unsigned)f2bf(s6) | ((unsigned)f2bf(s7) << 16);
        *(uint4*)&hlds[wave * 2 + 1][fq * 8] = u;
    }
    __syncthreads();

    // ---- phase B: dual GEMM over the block's 16 h rows
    int t4   = wave >> 1;                     // column tile 0..3
    int kind = wave & 1;                      // 0 -> hr (fp32), 1 -> hn (bf16)
    int rrow = lane & 15;
    int kg   = lane >> 4;
    bf16x8 a0 = *(const bf16x8*)&hlds[rrow][kg * 8];
    bf16x8 a1 = *(const bf16x8*)&hlds[rrow][32 + kg * 8];
    const unsigned short* Wt = wt + (2 + kind) * D * D;
    int c = t4 * 16 + rrow;
    bf16x8 bw0 = *(const bf16x8*)(Wt + c * D + kg * 8);
    bf16x8 bw1 = *(const bf16x8*)(Wt + c * D + 32 + kg * 8);
    f32x4 acc;
    acc[0] = 0.f; acc[1] = 0.f; acc[2] = 0.f; acc[3] = 0.f;
    acc = __builtin_amdgcn_mfma_f32_16x16x32_bf16(a0, bw0, acc, 0, 0, 0);
    acc = __builtin_amdgcn_mfma_f32_16x16x32_bf16(a1, bw1, acc, 0, 0, 0);
    if (kind == 0) {
#pragma unroll
        for (int i = 0; i < 4; i++)
            hr[(size_t)(n0 + kg * 4 + i) * D + c] = acc[i];
    } else {
#pragma unroll
        for (int i = 0; i < 4; i++)
            hn[(size_t)(n0 + kg * 4 + i) * D + c] = f2bf(acc[i]);
    }
}

// ---------- Gather 2 (verified R8 2-node form) + final epilogue -------------
__global__ void __launch_bounds__(256) gather2_out(
    const unsigned short* __restrict__ Gsrc, const float* __restrict__ Root,
    const float* __restrict__ bias,
    const int* __restrict__ startEnd, const int* __restrict__ csr,
    float* __restrict__ outF) {
    int tid = threadIdx.x;
    int wave = tid >> 6, lane = tid & 63;
    int nA = blockIdx.x * 8 + wave * 2;
    int nB = nA + 1;
    int sub = lane >> 3, fq = lane & 7;

    int4 se = *(const int4*)(startEnd + nA * 2);
    int jbA = se.x, jeA = se.y, jbB = se.z, jeB = se.w;

    float4 xA0, xA1, xB0, xB1, b0, b1;
    if (sub == 0) {
        const float* rpA = Root + (size_t)nA * D + fq * 8;
        const float* rpB = Root + (size_t)nB * D + fq * 8;
        xA0 = *(const float4*)rpA; xA1 = *(const float4*)(rpA + 4);
        xB0 = *(const float4*)rpB; xB1 = *(const float4*)(rpB + 4);
        b0 = ((const float4*)bias)[fq * 2];
        b1 = ((const float4*)bias)[fq * 2 + 1];
    }

    float aA0=0.f,aA1=0.f,aA2=0.f,aA3=0.f,aA4=0.f,aA5=0.f,aA6=0.f,aA7=0.f;
    float aB0=0.f,aB1=0.f,aB2=0.f,aB3=0.f,aB4=0.f,aB5=0.f,aB6=0.f,aB7=0.f;

    while (jbA < jeA || jbB < jeB) {
        int pA = 0, pB = 0, mA = 0, mB = 0;
        if (jbA < jeA) {
            int idx = jbA + lane;
            pA = csr[idx < jeA ? idx : (jeA - 1)];
            mA = min(64, jeA - jbA);
        }
        if (jbB < jeB) {
            int idx = jbB + lane;
            pB = csr[idx < jeB ? idx : (jeB - 1)];
            mB = min(64, jeB - jbB);
        }
        if (mA) {
            int b = 0;
            for (; b + 16 <= mA; b += 16) {
                int i0 = __shfl(pA, b + sub, 64);
                int i1 = __shfl(pA, b + 8 + sub, 64);
                uint4 u0 = *(const uint4*)(Gsrc + i0 * D + fq * 8);
                uint4 u1 = *(const uint4*)(Gsrc + i1 * D + fq * 8);
                aA0 += bflo(u0.x) + bflo(u1.x);  aA1 += bfhi(u0.x) + bfhi(u1.x);
                aA2 += bflo(u0.y) + bflo(u1.y);  aA3 += bfhi(u0.y) + bfhi(u1.y);
                aA4 += bflo(u0.z) + bflo(u1.z);  aA5 += bfhi(u0.z) + bfhi(u1.z);
                aA6 += bflo(u0.w) + bflo(u1.w);  aA7 += bfhi(u0.w) + bfhi(u1.w);
            }
            for (; b < mA; b += 8) {
                int sidx = b + sub;
                int scl = sidx < mA ? sidx : (mA - 1);
                int i0 = __shfl(pA, scl, 64);
                if (sidx < mA) {
                    uint4 u = *(const uint4*)(Gsrc + i0 * D + fq * 8);
                    aA0 += bflo(u.x); aA1 += bfhi(u.x);
                    aA2 += bflo(u.y); aA3 += bfhi(u.y);
                    aA4 += bflo(u.z); aA5 += bfhi(u.z);
                    aA6 += bflo(u.w); aA7 += bfhi(u.w);
                }
            }
        }
        if (mB) {
            int b = 0;
            for (; b + 16 <= mB; b += 16) {
                int i0 = __shfl(pB, b + sub, 64);
                int i1 = __shfl(pB, b + 8 + sub, 64);
                uint4 u0 = *(const uint4*)(Gsrc + i0 * D + fq * 8);
                uint4 u1 = *(const uint4*)(Gsrc + i1 * D + fq * 8);
                aB0 += bflo(u0.x) + bflo(u1.x);  aB1 += bfhi(u0.x) + bfhi(u1.x);
                aB2 += bflo(u0.y) + bflo(u1.y);  aB3 += bfhi(u0.y) + bfhi(u1.y);
                aB4 += bflo(u0.z) + bflo(u1.z);  aB5 += bfhi(u0.z) + bfhi(u1.z);
                aB6 += bflo(u0.w) + bflo(u1.w);  aB7 += bfhi(u0.w) + bfhi(u1.w);
            }
            for (; b < mB; b += 8) {
                int sidx = b + sub;
                int scl = sidx < mB ? sidx : (mB - 1);
                int i0 = __shfl(pB, scl, 64);
                if (sidx < mB) {
                    uint4 u = *(const uint4*)(Gsrc + i0 * D + fq * 8);
                    aB0 += bflo(u.x); aB1 += bfhi(u.x);
                    aB2 += bflo(u.y); aB3 += bfhi(u.y);
                    aB4 += bflo(u.z); aB5 += bfhi(u.z);
                    aB6 += bflo(u.w); aB7 += bfhi(u.w);
                }
            }
        }
        jbA += 64; jbB += 64;
    }

#pragma unroll
    for (int mk = 8; mk <= 32; mk <<= 1) {
        aA0 += __shfl_xor(aA0, mk, 64); aA1 += __shfl_xor(aA1, mk, 64);
        aA2 += __shfl_xor(aA2, mk, 64); aA3 += __shfl_xor(aA3, mk, 64);
        aA4 += __shfl_xor(aA4, mk, 64); aA5 += __shfl_xor(aA5, mk, 64);
        aA6 += __shfl_xor(aA6, mk, 64); aA7 += __shfl_xor(aA7, mk, 64);
        aB0 += __shfl_xor(aB0, mk, 64); aB1 += __shfl_xor(aB1, mk, 64);
        aB2 += __shfl_xor(aB2, mk, 64); aB3 += __shfl_xor(aB3, mk, 64);
        aB4 += __shfl_xor(aB4, mk, 64); aB5 += __shfl_xor(aB5, mk, 64);
        aB6 += __shfl_xor(aB6, mk, 64); aB7 += __shfl_xor(aB7, mk, 64);
    }
    if (sub == 0) {
        float4 w0, w1;
        w0.x = aA0 + xA0.x + b0.x; w0.y = aA1 + xA0.y + b0.y;
        w0.z = aA2 + xA0.z + b0.z; w0.w = aA3 + xA0.w + b0.w;
        w1.x = aA4 + xA1.x + b1.x; w1.y = aA5 + xA1.y + b1.y;
        w1.z = aA6 + xA1.z + b1.z; w1.w = aA7 + xA1.w + b1.w;
        *(float4*)(outF + (size_t)nA * D + fq * 8) = w0;
        *(float4*)(outF + (size_t)nA * D + fq * 8 + 4) = w1;
        w0.x = aB0 + xB0.x + b0.x; w0.y = aB1 + xB0.y + b0.y;
        w0.z = aB2 + xB0.z + b0.z; w0.w = aB3 + xB0.w + b0.w;
        w1.x = aB4 + xB1.x + b1.x; w1.y = aB5 + xB1.y + b1.y;
        w1.z = aB6 + xB1.z + b1.z; w1.w = aB7 + xB1.w + b1.w;
        *(float4*)(outF + (size_t)nB * D + fq * 8) = w0;
        *(float4*)(outF + (size_t)nB * D + fq * 8 + 4) = w1;
    }
}

// ---------- launch ----------------------------------------------------------
extern "C" void kernel_launch(void* const* d_in, const int* in_sizes, int n_in,
                              void* d_out, int out_size, void* d_ws, size_t ws_size,
                              hipStream_t stream) {
    const float* x   = (const float*)d_in[0];
    const int*   edg = (const int*)d_in[1];
    const float* W1r = (const float*)d_in[2];
    const float* W1n = (const float*)d_in[3];
    const float* b1  = (const float*)d_in[4];
    const float* W2r = (const float*)d_in[5];
    const float* W2n = (const float*)d_in[6];
    const float* b2  = (const float*)d_in[7];
    float* out = (float*)d_out;

    const int* src = edg;
    const int* dst = edg + N_EDGES;

    // ws (256 MiB) — non-overlapping layout (hbf eliminated).
    int* W              = (int*)d_ws;
    int* cursorPad      = W;                          // NBUCKETS*16 ints
    int* staged         = W + NBUCKETS * 16;          // NBUCKETS*BCAP ints
    int* csr            = staged + NBUCKETS * BCAP;   // NBUCKETS*BCAP ints
    int* startEnd       = csr + NBUCKETS * BCAP;      // N_NODES int2 (packed)
    float* xr           = (float*)(startEnd + 2 * N_NODES); // fp32 [N][64]
    unsigned short* xn  = (unsigned short*)(xr + (size_t)N_NODES * D); // bf16 x@W1n
    float* hr           = (float*)(xn + (size_t)N_NODES * D);          // fp32 h@W2r
    unsigned short* hn  = (unsigned short*)(hr + (size_t)N_NODES * D); // bf16 h@W2n
    unsigned short* wt  = hn + (size_t)N_NODES * D;   // 4x[64][64] bf16 W^T

    // prep: zero cursors + bf16 W^T
    prep_kernel<<<5, 256, 0, stream>>>(W1r, W1n, W2r, W2n, cursorPad, wt);

    // [scatter || layer-1 dual MFMA GEMM]  (xr = x@W1r fp32, xn = x@W1n bf16)
    scatter_gemm1<<<SBLOCKS + MB, 256, 0, stream>>>(
        src, dst, cursorPad, staged, x, wt, xr, xn);

    csr_build_kernel<<<NBUCKETS, 256, 0, stream>>>(cursorPad, staged, csr,
                                                   startEnd);

    // fused: h = relu(xr + segsum(xn[src]) + b1)  ->  hr = h@W2r, hn = h@W2n
    gather1_gemm2<<<N_NODES / 16, 512, 0, stream>>>(
        xn, xr, b1, startEnd, csr, wt, hr, hn);

    // out = hr + segsum(hn[src]) + b2
    gather2_out<<<N_NODES / 8, 256, 0, stream>>>(
        hn, hr, b2, startEnd, csr, out);
}